// Round 4
// baseline (665.831 us; speedup 1.0000x reference)
//
#include <hip/hip_runtime.h>

#define NNODES 100000
#define NEDGES 1600000
#define NTILES (NEDGES / 16)
#define DIM    128
#define NF     64
#define NG     50
#define H1P    20   // h1buf row stride in shorts (verified conflict-free in round 3)

constexpr float F_CUTOFF = 5.0f;
constexpr float F_DELTA  = F_CUTOFF / (NG - 1);
constexpr float F_COEFF  = -0.5f / (F_DELTA * F_DELTA);
constexpr float F_PI     = 3.14159265358979323846f;

typedef __attribute__((ext_vector_type(8))) short short8v;
typedef __attribute__((ext_vector_type(4))) float f32x4;
typedef __attribute__((ext_vector_type(2))) int int2v;

__device__ inline unsigned short f2bf(float x) {
  unsigned int u = __float_as_uint(x);
  unsigned int r = (u + 0x7fffu + ((u >> 16) & 1u)) >> 16;
  return (unsigned short)r;
}
__device__ inline float bf2f(unsigned int lo16) {
  return __uint_as_float(lo16 << 16);
}

// ---------------- kernel 1: h[n][f] = sum_k x[n][k] * lin1_w[f][k]  (bf16 out) ----------------
__global__ __launch_bounds__(256) void k_lin1(
    const float* __restrict__ x, const float* __restrict__ w1,
    unsigned short* __restrict__ h) {
  __shared__ __align__(16) float sw[NF][DIM + 4];
  for (int i = threadIdx.x; i < NF * DIM; i += 256)
    sw[i >> 7][i & 127] = w1[i];
  __syncthreads();
  const int wave = threadIdx.x >> 6, lane = threadIdx.x & 63;
  const int nIter = NNODES / 4;
  for (int it = blockIdx.x * 4 + wave; it < nIter; it += gridDim.x * 4) {
    const int n0 = it * 4;
    const float4* x0 = (const float4*)(x + (size_t)(n0 + 0) * DIM);
    const float4* x1 = (const float4*)(x + (size_t)(n0 + 1) * DIM);
    const float4* x2 = (const float4*)(x + (size_t)(n0 + 2) * DIM);
    const float4* x3 = (const float4*)(x + (size_t)(n0 + 3) * DIM);
    float a0 = 0.f, a1 = 0.f, a2 = 0.f, a3 = 0.f;
#pragma unroll 8
    for (int k4 = 0; k4 < DIM / 4; ++k4) {
      const float4 wv = *(const float4*)&sw[lane][k4 * 4];
      const float4 v0 = x0[k4], v1 = x1[k4], v2 = x2[k4], v3 = x3[k4];
      a0 = fmaf(v0.x, wv.x, a0); a0 = fmaf(v0.y, wv.y, a0);
      a0 = fmaf(v0.z, wv.z, a0); a0 = fmaf(v0.w, wv.w, a0);
      a1 = fmaf(v1.x, wv.x, a1); a1 = fmaf(v1.y, wv.y, a1);
      a1 = fmaf(v1.z, wv.z, a1); a1 = fmaf(v1.w, wv.w, a1);
      a2 = fmaf(v2.x, wv.x, a2); a2 = fmaf(v2.y, wv.y, a2);
      a2 = fmaf(v2.z, wv.z, a2); a2 = fmaf(v2.w, wv.w, a2);
      a3 = fmaf(v3.x, wv.x, a3); a3 = fmaf(v3.y, wv.y, a3);
      a3 = fmaf(v3.z, wv.z, a3); a3 = fmaf(v3.w, wv.w, a3);
    }
    h[(size_t)(n0 + 0) * NF + lane] = f2bf(a0);
    h[(size_t)(n0 + 1) * NF + lane] = f2bf(a1);
    h[(size_t)(n0 + 2) * NF + lane] = f2bf(a2);
    h[(size_t)(n0 + 3) * NF + lane] = f2bf(a3);
  }
}

// ---------------- histogram of dst ----------------
__global__ __launch_bounds__(256) void k_hist(
    const int* __restrict__ ei, int* __restrict__ counts) {
  const int e = blockIdx.x * 256 + threadIdx.x;
  if (e < NEDGES) atomicAdd(&counts[ei[NEDGES + e]], 1);
}

// ---------------- single-block exclusive scan: head[n] = sum_{i<n} counts[i] ----------------
__global__ __launch_bounds__(1024) void k_scan(
    const int* __restrict__ counts, int* __restrict__ head) {
  __shared__ int ssum[1024];
  const int t = threadIdx.x;
  const int CH = (NNODES + 1023) / 1024;  // 98
  const int lo = t * CH, hi = (lo + CH < NNODES) ? lo + CH : NNODES;
  int s = 0;
  for (int i = lo; i < hi; ++i) s += counts[i];
  ssum[t] = s;
  __syncthreads();
  for (int off = 1; off < 1024; off <<= 1) {
    int xv = (t >= off) ? ssum[t - off] : 0;
    __syncthreads();
    ssum[t] += xv;
    __syncthreads();
  }
  int run = ssum[t] - s;  // exclusive base for this chunk
  for (int i = lo; i < hi; ++i) { head[i] = run; run += counts[i]; }
}

// ---------------- reorder edges into dst-sorted arrays ----------------
__global__ __launch_bounds__(256) void k_reorder(
    const int* __restrict__ ei, const float* __restrict__ ea,
    int* __restrict__ head, float* __restrict__ sea,
    int* __restrict__ ssrc, int* __restrict__ sdst) {
  const int e = blockIdx.x * 256 + threadIdx.x;
  if (e < NEDGES) {
    const int dst = ei[NEDGES + e];
    const int pos = atomicAdd(&head[dst], 1);
    sea[pos]  = ea[e];
    ssrc[pos] = ei[e];
    sdst[pos] = dst;
  }
}

// ---------------- kernel 2: MFMA edge MLP on dst-sorted edges + run-merged scatter ----------------
// 16 consecutive sorted edges per tile; chunked tile->wave assignment.
// Phase2 tiles filter-pair permuted: lane holds filters (2lo,2lo+1) and (32+2lo,33+2lo).
// C/D layout (verified): col = lane&15, row = (lane>>4)*4 + reg.
__global__ __launch_bounds__(256, 4) void k_edge_mfma(
    const float* __restrict__ sea, const int* __restrict__ ssrc,
    const int* __restrict__ sdst, const unsigned short* __restrict__ hbf,
    const float* __restrict__ w1, const float* __restrict__ b1,
    const float* __restrict__ w2, const float* __restrict__ b2,
    unsigned short* __restrict__ agg) {
  __shared__ __align__(16) unsigned short h1buf[4][NF][H1P];

  const int wave = threadIdx.x >> 6, lane = threadIdx.x & 63;
  const int lo = lane & 15, g = lane >> 4;

  // --- B1 fragments: B[k=gauss][n=f], f = t*16+lo, zero-padded past NG
  short8v B1[4][2];
#pragma unroll
  for (int t = 0; t < 4; ++t)
#pragma unroll
    for (int s = 0; s < 2; ++s) {
      short8v f8;
#pragma unroll
      for (int i = 0; i < 8; ++i) {
        const int gg = s * 32 + g * 8 + i;
        const int f  = t * 16 + lo;
        f8[i] = (gg < NG) ? (short)f2bf(w1[f * NG + gg]) : (short)0;
      }
      B1[t][s] = f8;
    }
  // --- B2 fragments: output filter j = (t>>1)*32 + 2*lo + (t&1)
  short8v B2[4][2];
#pragma unroll
  for (int t = 0; t < 4; ++t)
#pragma unroll
    for (int s = 0; s < 2; ++s) {
      short8v f8;
#pragma unroll
      for (int i = 0; i < 8; ++i) {
        const int f_in = s * 32 + g * 8 + i;
        const int j = (t >> 1) * 32 + 2 * lo + (t & 1);
        f8[i] = (short)f2bf(w2[j * NF + f_in]);
      }
      B2[t][s] = f8;
    }
  float b1v[4], b2v[4];
#pragma unroll
  for (int t = 0; t < 4; ++t) {
    b1v[t] = b1[t * 16 + lo];
    b2v[t] = b2[(t >> 1) * 32 + 2 * lo + (t & 1)];
  }

  const float l2e_coeff = F_COEFF * 1.44269504088896341f;

  // chunked assignment: contiguous tiles per wave -> dst-local atomics
  const int wid = blockIdx.x * 4 + wave;
  const int TPW = (NTILES + 8191) / 8192;  // 13
  const int it0 = wid * TPW;
  const int it1 = (it0 + TPW < NTILES) ? it0 + TPW : NTILES;
  if (it0 >= it1) return;

  int4 src4 = *(const int4*)&ssrc[it0 * 16 + g * 4];  // prefetch first tile

  for (int it = it0; it < it1; ++it) {
    const int e0 = it * 16;
    const int4 s4 = src4;

    // ---- EARLY gathers for this tile (hide under MLP)
    unsigned int hp0[4], hp1[4];
    {
      const int sv[4] = {s4.x, s4.y, s4.z, s4.w};
#pragma unroll
      for (int r = 0; r < 4; ++r) {
        const unsigned short* hsrc = hbf + (size_t)sv[r] * NF + 2 * lo;
        hp0[r] = *(const unsigned int*)(hsrc);
        hp1[r] = *(const unsigned int*)(hsrc + 32);
      }
    }
    // ---- prefetch next tile's src4
    {
      const int itn = (it + 1 < it1) ? it + 1 : it;
      src4 = *(const int4*)&ssrc[itn * 16 + g * 4];
    }
    // ---- per-slot dist + dst (group-uniform 16B broadcasts)
    const float  d  = sea[e0 + lo];                      // edge lo, for A1 rows
    const float4 d4 = *(const float4*)&sea[e0 + g * 4];  // this group's 4 edges
    const int4   dv = *(const int4*)&sdst[e0 + g * 4];

    // ---- A1: gaussian smearing into fragment layout
    short8v A1[2];
#pragma unroll
    for (int s = 0; s < 2; ++s) {
      short8v f8;
#pragma unroll
      for (int i = 0; i < 8; ++i) {
        const int gg = s * 32 + g * 8 + i;
        const float t0 = d - (float)gg * F_DELTA;
        const float sm = exp2f(l2e_coeff * t0 * t0);
        f8[i] = (gg < NG) ? (short)f2bf(sm) : (short)0;
      }
      A1[s] = f8;
    }

    // ---- phase 1 MFMA
    f32x4 acc1[4];
#pragma unroll
    for (int t = 0; t < 4; ++t) {
      f32x4 z = {0.f, 0.f, 0.f, 0.f};
      z = __builtin_amdgcn_mfma_f32_16x16x32_bf16(A1[0], B1[t][0], z, 0, 0, 0);
      z = __builtin_amdgcn_mfma_f32_16x16x32_bf16(A1[1], B1[t][1], z, 0, 0, 0);
      acc1[t] = z;
    }

    // ---- relu+bias, pack, LDS transpose store
#pragma unroll
    for (int t = 0; t < 4; ++t) {
      const float v0 = fmaxf(acc1[t][0] + b1v[t], 0.f);
      const float v1 = fmaxf(acc1[t][1] + b1v[t], 0.f);
      const float v2 = fmaxf(acc1[t][2] + b1v[t], 0.f);
      const float v3 = fmaxf(acc1[t][3] + b1v[t], 0.f);
      int2v pk;
      pk[0] = (int)((unsigned)f2bf(v0) | ((unsigned)f2bf(v1) << 16));
      pk[1] = (int)((unsigned)f2bf(v2) | ((unsigned)f2bf(v3) << 16));
      *(int2v*)&h1buf[wave][t * 16 + lo][g * 4] = pk;
    }

    // ---- A2: column slice
    short8v A2[2];
#pragma unroll
    for (int s = 0; s < 2; ++s) {
      short8v f8;
#pragma unroll
      for (int i = 0; i < 8; ++i)
        f8[i] = (short)h1buf[wave][s * 32 + g * 8 + i][lo];
      A2[s] = f8;
    }

    // ---- phase 2 MFMA
    f32x4 acc2[4];
#pragma unroll
    for (int t = 0; t < 4; ++t) {
      f32x4 z = {0.f, 0.f, 0.f, 0.f};
      z = __builtin_amdgcn_mfma_f32_16x16x32_bf16(A2[0], B2[t][0], z, 0, 0, 0);
      z = __builtin_amdgcn_mfma_f32_16x16x32_bf16(A2[1], B2[t][1], z, 0, 0, 0);
      acc2[t] = z;
    }

    // ---- messages m[r][t]: edge g*4+r, filters (2lo,2lo+1,32+2lo,33+2lo)
    float m[4][4];
    const float dd[4] = {d4.x, d4.y, d4.z, d4.w};
#pragma unroll
    for (int r = 0; r < 4; ++r) {
      const float C = 0.5f * (__cosf(dd[r] * (F_PI / F_CUTOFF)) + 1.0f);
      m[r][0] = bf2f(hp0[r] & 0xffffu) * (acc2[0][r] + b2v[0]) * C;
      m[r][1] = bf2f(hp0[r] >> 16)     * (acc2[1][r] + b2v[1]) * C;
      m[r][2] = bf2f(hp1[r] & 0xffffu) * (acc2[2][r] + b2v[2]) * C;
      m[r][3] = bf2f(hp1[r] >> 16)     * (acc2[3][r] + b2v[3]) * C;
    }

    // ---- in-lane run merge over the 4 consecutive sorted edges, flush leaders
    const int dvv[4] = {dv.x, dv.y, dv.z, dv.w};
    float run[4][4];
#pragma unroll
    for (int t = 0; t < 4; ++t) run[3][t] = m[3][t];
#pragma unroll
    for (int r = 2; r >= 0; --r) {
      const bool join = (dvv[r + 1] == dvv[r]);
#pragma unroll
      for (int t = 0; t < 4; ++t)
        run[r][t] = m[r][t] + (join ? run[r + 1][t] : 0.f);
    }
#pragma unroll
    for (int r = 0; r < 4; ++r) {
      const bool leader = (r == 0) || (dvv[r] != dvv[r - 1]);
      if (leader) {
        unsigned short* ap = agg + (size_t)dvv[r] * NF + 2 * lo;
        const unsigned int pk0 = (unsigned)f2bf(run[r][0]) | ((unsigned)f2bf(run[r][1]) << 16);
        const unsigned int pk1 = (unsigned)f2bf(run[r][2]) | ((unsigned)f2bf(run[r][3]) << 16);
        asm volatile("global_atomic_pk_add_bf16 %0, %1, off" :: "v"(ap), "v"(pk0));
        asm volatile("global_atomic_pk_add_bf16 %0, %1, off" :: "v"(ap + 32), "v"(pk1));
      }
    }
  }
}

// ---------------- kernel 3: out[n][d] = x[n][d] + relu(b[d] + agg[n,:] . lin2_w[d,:]) ----------------
__global__ __launch_bounds__(256) void k_out(
    const float* __restrict__ x, const unsigned short* __restrict__ agg,
    const float* __restrict__ w2, const float* __restrict__ b,
    float* __restrict__ out) {
  __shared__ __align__(16) float sw[DIM][NF + 4];
  __shared__ __align__(16) float sa[4][4][NF];
  for (int i = threadIdx.x; i < DIM * NF; i += 256)
    sw[i >> 6][i & 63] = w2[i];
  __syncthreads();
  const int wave = threadIdx.x >> 6, lane = threadIdx.x & 63;
  const float bias0 = b[lane], bias1 = b[lane + 64];
  const int nIter = NNODES / 4;
  for (int it = blockIdx.x * 4 + wave; it < nIter; it += gridDim.x * 4) {
    const int n0 = it * 4;
#pragma unroll
    for (int i = 0; i < 4; ++i)
      sa[wave][i][lane] = bf2f((unsigned)agg[(size_t)(n0 + i) * NF + lane]);
    float acc[8];
#pragma unroll
    for (int i = 0; i < 4; ++i) { acc[2 * i] = bias0; acc[2 * i + 1] = bias1; }
#pragma unroll
    for (int j4 = 0; j4 < NF / 4; ++j4) {
      const float4 wv0 = *(const float4*)&sw[lane][j4 * 4];
      const float4 wv1 = *(const float4*)&sw[lane + 64][j4 * 4];
#pragma unroll
      for (int i = 0; i < 4; ++i) {
        const float4 av = *(const float4*)&sa[wave][i][j4 * 4];
        acc[2 * i]     = fmaf(wv0.x, av.x, acc[2 * i]);
        acc[2 * i]     = fmaf(wv0.y, av.y, acc[2 * i]);
        acc[2 * i]     = fmaf(wv0.z, av.z, acc[2 * i]);
        acc[2 * i]     = fmaf(wv0.w, av.w, acc[2 * i]);
        acc[2 * i + 1] = fmaf(wv1.x, av.x, acc[2 * i + 1]);
        acc[2 * i + 1] = fmaf(wv1.y, av.y, acc[2 * i + 1]);
        acc[2 * i + 1] = fmaf(wv1.z, av.z, acc[2 * i + 1]);
        acc[2 * i + 1] = fmaf(wv1.w, av.w, acc[2 * i + 1]);
      }
    }
#pragma unroll
    for (int i = 0; i < 4; ++i) {
      const size_t base = (size_t)(n0 + i) * DIM;
      out[base + lane]      = x[base + lane]      + fmaxf(acc[2 * i],     0.f);
      out[base + 64 + lane] = x[base + 64 + lane] + fmaxf(acc[2 * i + 1], 0.f);
    }
  }
}

extern "C" void kernel_launch(void* const* d_in, const int* in_sizes, int n_in,
                              void* d_out, int out_size, void* d_ws, size_t ws_size,
                              hipStream_t stream) {
  const float* x   = (const float*)d_in[0];
  const int*   ei  = (const int*)  d_in[1];
  const float* ea  = (const float*)d_in[3];   // edge_attr == edge_weight (same dist)
  const float* l1w = (const float*)d_in[4];
  const float* l2w = (const float*)d_in[5];
  const float* l2b = (const float*)d_in[6];
  const float* e1w = (const float*)d_in[7];
  const float* e1b = (const float*)d_in[8];
  const float* e2w = (const float*)d_in[9];
  const float* e2b = (const float*)d_in[10];
  float* out = (float*)d_out;

  // ws carve (all sizes multiple of 256B): total ~45.6 MB
  char* p = (char*)d_ws;
  unsigned short* hbf  = (unsigned short*)p; p += (size_t)NNODES * NF * 2;   // 12.8 MB
  unsigned short* agg  = (unsigned short*)p; p += (size_t)NNODES * NF * 2;   // 12.8 MB
  int*   counts        = (int*)p;            p += (size_t)NNODES * 4;        // 0.4 MB
  int*   head          = (int*)p;            p += (size_t)NNODES * 4;        // 0.4 MB
  float* sea           = (float*)p;          p += (size_t)NEDGES * 4;        // 6.4 MB
  int*   ssrc          = (int*)p;            p += (size_t)NEDGES * 4;        // 6.4 MB
  int*   sdst          = (int*)p;            p += (size_t)NEDGES * 4;        // 6.4 MB

  hipMemsetAsync(counts, 0, sizeof(int) * (size_t)NNODES, stream);
  hipMemsetAsync(agg, 0, sizeof(unsigned short) * (size_t)NNODES * NF, stream);

  k_lin1   <<<2048, 256, 0, stream>>>(x, l1w, hbf);
  k_hist   <<<(NEDGES + 255) / 256, 256, 0, stream>>>(ei, counts);
  k_scan   <<<1, 1024, 0, stream>>>(counts, head);
  k_reorder<<<(NEDGES + 255) / 256, 256, 0, stream>>>(ei, ea, head, sea, ssrc, sdst);
  k_edge_mfma<<<2048, 256, 0, stream>>>(sea, ssrc, sdst, hbf, e1w, e1b, e2w, e2b, agg);
  k_out    <<<2048, 256, 0, stream>>>(x, agg, l2w, l2b, out);
}

// Round 5
// 608.267 us; speedup vs baseline: 1.0946x; 1.0946x over previous
//
#include <hip/hip_runtime.h>
#include <hip/hip_bf16.h>

#define NNODES 100000
#define NEDGES 1600000
#define DIM    128
#define NF     64
#define NG     50
#define H1P    20        // h1buf row stride in shorts (0 conflicts measured r3/r4)
#define EPG    52        // edges per 16-lane group chunk (13 iters x 4)
#define EPW    208       // edges per wave (4 groups)
#define NWAVES 8192      // 2048 blocks x 4 waves
#define EPTOT  1703936   // NWAVES * EPW  (>= NEDGES, OOB slots masked)

constexpr float F_CUTOFF = 5.0f;
constexpr float F_DELTA  = F_CUTOFF / (NG - 1);
constexpr float F_COEFF  = -0.5f / (F_DELTA * F_DELTA);
constexpr float F_PI     = 3.14159265358979323846f;

typedef __attribute__((ext_vector_type(8))) short short8v;
typedef __attribute__((ext_vector_type(4))) float f32x4;
typedef __attribute__((ext_vector_type(2))) int int2v;

__device__ inline unsigned short f2bf(float x) {
  __hip_bfloat16 h = __float2bfloat16(x);
  return *reinterpret_cast<unsigned short*>(&h);
}
__device__ inline unsigned pkbf(float a, float b) {
  float2 f2; f2.x = a; f2.y = b;
  __hip_bfloat162 h2 = __float22bfloat162_rn(f2);
  return *reinterpret_cast<unsigned*>(&h2);
}
__device__ inline float bf2f(unsigned int lo16) {
  return __uint_as_float(lo16 << 16);
}

// ---------------- kernel 1: h[n][f] = sum_k x[n][k] * lin1_w[f][k]  (bf16 out) ----------------
__global__ __launch_bounds__(256) void k_lin1(
    const float* __restrict__ x, const float* __restrict__ w1,
    unsigned short* __restrict__ h) {
  __shared__ __align__(16) float sw[NF][DIM + 4];
  for (int i = threadIdx.x; i < NF * DIM; i += 256)
    sw[i >> 7][i & 127] = w1[i];
  __syncthreads();
  const int wave = threadIdx.x >> 6, lane = threadIdx.x & 63;
  const int nIter = NNODES / 4;
  for (int it = blockIdx.x * 4 + wave; it < nIter; it += gridDim.x * 4) {
    const int n0 = it * 4;
    const float4* x0 = (const float4*)(x + (size_t)(n0 + 0) * DIM);
    const float4* x1 = (const float4*)(x + (size_t)(n0 + 1) * DIM);
    const float4* x2 = (const float4*)(x + (size_t)(n0 + 2) * DIM);
    const float4* x3 = (const float4*)(x + (size_t)(n0 + 3) * DIM);
    float a0 = 0.f, a1 = 0.f, a2 = 0.f, a3 = 0.f;
#pragma unroll 8
    for (int k4 = 0; k4 < DIM / 4; ++k4) {
      const float4 wv = *(const float4*)&sw[lane][k4 * 4];
      const float4 v0 = x0[k4], v1 = x1[k4], v2 = x2[k4], v3 = x3[k4];
      a0 = fmaf(v0.x, wv.x, a0); a0 = fmaf(v0.y, wv.y, a0);
      a0 = fmaf(v0.z, wv.z, a0); a0 = fmaf(v0.w, wv.w, a0);
      a1 = fmaf(v1.x, wv.x, a1); a1 = fmaf(v1.y, wv.y, a1);
      a1 = fmaf(v1.z, wv.z, a1); a1 = fmaf(v1.w, wv.w, a1);
      a2 = fmaf(v2.x, wv.x, a2); a2 = fmaf(v2.y, wv.y, a2);
      a2 = fmaf(v2.z, wv.z, a2); a2 = fmaf(v2.w, wv.w, a2);
      a3 = fmaf(v3.x, wv.x, a3); a3 = fmaf(v3.y, wv.y, a3);
      a3 = fmaf(v3.w, wv.w, a3); a3 = fmaf(v3.z, wv.z, a3);
    }
    h[(size_t)(n0 + 0) * NF + lane] = f2bf(a0);
    h[(size_t)(n0 + 1) * NF + lane] = f2bf(a1);
    h[(size_t)(n0 + 2) * NF + lane] = f2bf(a2);
    h[(size_t)(n0 + 3) * NF + lane] = f2bf(a3);
  }
}

// ---------------- histogram of dst ----------------
__global__ __launch_bounds__(256) void k_hist(
    const int* __restrict__ ei, int* __restrict__ counts) {
  const int e = blockIdx.x * 256 + threadIdx.x;
  if (e < NEDGES) atomicAdd(&counts[ei[NEDGES + e]], 1);
}

// ---------------- in-place exclusive scan: counts[n] -> sum_{i<n} counts[i] ----------------
__global__ __launch_bounds__(1024) void k_scan(int* __restrict__ counts) {
  __shared__ int ssum[1024];
  const int t = threadIdx.x;
  const int CH = (NNODES + 1023) / 1024;  // 98
  const int lo = t * CH, hi = (lo + CH < NNODES) ? lo + CH : NNODES;
  int s = 0;
  for (int i = lo; i < hi; ++i) s += counts[i];
  ssum[t] = s;
  __syncthreads();
  for (int off = 1; off < 1024; off <<= 1) {
    int xv = (t >= off) ? ssum[t - off] : 0;
    __syncthreads();
    ssum[t] += xv;
    __syncthreads();
  }
  int run = ssum[t] - s;  // exclusive base for this chunk
  for (int i = lo; i < hi; ++i) { const int c = counts[i]; counts[i] = run; run += c; }
}

// ---------------- reorder into dst-sorted arrays (living in d_out dead space) ----------------
__global__ __launch_bounds__(256) void k_reorder(
    const int* __restrict__ ei, const float* __restrict__ ea,
    int* __restrict__ heads, int2* __restrict__ sd8, int* __restrict__ sdst) {
  const int e = blockIdx.x * 256 + threadIdx.x;
  if (e < NEDGES) {
    const int dst = ei[NEDGES + e];
    const int pos = atomicAdd(&heads[dst], 1);
    int2 r; r.x = ei[e]; r.y = __float_as_int(ea[e]);
    sd8[pos] = r;
    sdst[pos] = dst;
  }
}

// ---------------- kernel 2: MFMA edge MLP, group-contiguous sorted chunks, carry-run flush ----------------
// Each 16-lane group owns EPG=52 consecutive sorted edges (4/iter x 13 iters); run sums are
// carried in registers across iterations and flushed with 2 pk-bf16 atomics per dst change.
// Phase2 tiles filter-pair permuted: lane holds filters (2lo,2lo+1) and (32+2lo,33+2lo).
// C/D layout (verified): col = lane&15, row = (lane>>4)*4 + reg.
__global__ __launch_bounds__(256) void k_edge_mfma(
    const int2* __restrict__ sd8, const int* __restrict__ sdst,
    const unsigned short* __restrict__ hbf,
    const float* __restrict__ w1, const float* __restrict__ b1,
    const float* __restrict__ w2, const float* __restrict__ b2,
    unsigned short* __restrict__ agg) {
  __shared__ __align__(16) unsigned short h1buf[4][NF][H1P];

  const int wave = threadIdx.x >> 6, lane = threadIdx.x & 63;
  const int lo = lane & 15, g = lane >> 4;

  // --- B1 fragments: B[k=gauss][n=f], f = t*16+lo, zero past NG
  short8v B1[4][2];
#pragma unroll
  for (int t = 0; t < 4; ++t)
#pragma unroll
    for (int s = 0; s < 2; ++s) {
      short8v f8;
#pragma unroll
      for (int i = 0; i < 8; ++i) {
        const int gg = s * 32 + g * 8 + i;
        const int f  = t * 16 + lo;
        f8[i] = (gg < NG) ? (short)f2bf(w1[f * NG + gg]) : (short)0;
      }
      B1[t][s] = f8;
    }
  // --- B2 fragments: output filter j = (t>>1)*32 + 2*lo + (t&1)
  short8v B2[4][2];
#pragma unroll
  for (int t = 0; t < 4; ++t)
#pragma unroll
    for (int s = 0; s < 2; ++s) {
      short8v f8;
#pragma unroll
      for (int i = 0; i < 8; ++i) {
        const int f_in = s * 32 + g * 8 + i;
        const int j = (t >> 1) * 32 + 2 * lo + (t & 1);
        f8[i] = (short)f2bf(w2[j * NF + f_in]);
      }
      B2[t][s] = f8;
    }
  float b1v[4], b2v[4];
#pragma unroll
  for (int t = 0; t < 4; ++t) {
    b1v[t] = b1[t * 16 + lo];
    b2v[t] = b2[(t >> 1) * 32 + 2 * lo + (t & 1)];
  }

  const float l2e  = F_COEFF * 1.44269504088896341f;
  const float goff = (float)(g * 8) * F_DELTA;

  const int wid   = blockIdx.x * 4 + wave;
  const int gbase = wid * EPW + g * EPG;                       // group's first slot
  const int lbase = wid * EPW + (lo >> 2) * EPG + (lo & 3);    // lane's A1-row slot base

  int run_dst = -1;
  float c0 = 0.f, c1 = 0.f, c2 = 0.f, c3 = 0.f;

  // 1-deep prefetch of broadcast loads
  int4 ra = *(const int4*)&sd8[gbase];
  int4 rb = *(const int4*)&sd8[gbase + 2];
  int4 dz = *(const int4*)&sdst[gbase];
  float dnx = __int_as_float(sd8[lbase].y);
  dnx = (lbase < NEDGES) ? dnx : 0.f;

#pragma unroll 1
  for (int it = 0; it < EPG / 4; ++it) {
    const int eg = gbase + it * 4;
    const int4 cra = ra, crb = rb, cdz = dz;
    const float d = dnx;
    {  // prefetch next (clamped: last iter re-loads itself, harmless)
      const int itn = (it + 1 < EPG / 4) ? it + 1 : it;
      const int egn = gbase + itn * 4;
      ra = *(const int4*)&sd8[egn];
      rb = *(const int4*)&sd8[egn + 2];
      dz = *(const int4*)&sdst[egn];
      const int lsn = lbase + itn * 4;
      float dn = __int_as_float(sd8[lsn].y);
      dnx = (lsn < NEDGES) ? dn : 0.f;
    }

    int   sv[4] = {cra.x, cra.z, crb.x, crb.z};
    float dd[4] = {__int_as_float(cra.y), __int_as_float(cra.w),
                   __int_as_float(crb.y), __int_as_float(crb.w)};
    int   dv[4] = {cdz.x, cdz.y, cdz.z, cdz.w};
#pragma unroll
    for (int r = 0; r < 4; ++r) {
      const bool val = (eg + r) < NEDGES;
      sv[r] = val ? sv[r] : 0;     // clamp gather address into hbf
      dv[r] = val ? dv[r] : -1;    // sentinel: never flushed
    }

    // ---- EARLY gathers (consumed at iteration tail, hidden under the MLP)
    unsigned hp0[4], hp1[4];
#pragma unroll
    for (int r = 0; r < 4; ++r) {
      const unsigned short* hs = hbf + (size_t)sv[r] * NF + 2 * lo;
      hp0[r] = *(const unsigned*)(hs);
      hp1[r] = *(const unsigned*)(hs + 32);
    }

    // ---- A1: gaussians straight into fragment layout (k>=NG columns are zero in B1)
    short8v A1[2];
#pragma unroll
    for (int s = 0; s < 2; ++s) {
      union { short8v v; unsigned u[4]; } au;
#pragma unroll
      for (int p = 0; p < 4; ++p) {
        const float off0 = goff + (float)(s * 32 + 2 * p) * F_DELTA;
        const float t0 = d - off0;
        const float t1 = d - (off0 + F_DELTA);
        au.u[p] = pkbf(exp2f(l2e * t0 * t0), exp2f(l2e * t1 * t1));
      }
      A1[s] = au.v;
    }

    // ---- phase 1 MFMA
    f32x4 acc1[4];
#pragma unroll
    for (int t = 0; t < 4; ++t) {
      f32x4 z = {0.f, 0.f, 0.f, 0.f};
      z = __builtin_amdgcn_mfma_f32_16x16x32_bf16(A1[0], B1[t][0], z, 0, 0, 0);
      z = __builtin_amdgcn_mfma_f32_16x16x32_bf16(A1[1], B1[t][1], z, 0, 0, 0);
      acc1[t] = z;
    }

    // ---- relu+bias, pack, LDS transpose store (f = t*16+lo, e = g*4..+3)
#pragma unroll
    for (int t = 0; t < 4; ++t) {
      const float v0 = fmaxf(acc1[t][0] + b1v[t], 0.f);
      const float v1 = fmaxf(acc1[t][1] + b1v[t], 0.f);
      const float v2 = fmaxf(acc1[t][2] + b1v[t], 0.f);
      const float v3 = fmaxf(acc1[t][3] + b1v[t], 0.f);
      int2v pk;
      pk[0] = (int)pkbf(v0, v1);
      pk[1] = (int)pkbf(v2, v3);
      *(int2v*)&h1buf[wave][t * 16 + lo][g * 4] = pk;
    }

    // ---- A2: column slice (e = lo, f_in = s*32+g*8+i)
    short8v A2[2];
#pragma unroll
    for (int s = 0; s < 2; ++s) {
      short8v f8;
#pragma unroll
      for (int i = 0; i < 8; ++i)
        f8[i] = (short)h1buf[wave][s * 32 + g * 8 + i][lo];
      A2[s] = f8;
    }

    // ---- phase 2 MFMA
    f32x4 acc2[4];
#pragma unroll
    for (int t = 0; t < 4; ++t) {
      f32x4 z = {0.f, 0.f, 0.f, 0.f};
      z = __builtin_amdgcn_mfma_f32_16x16x32_bf16(A2[0], B2[t][0], z, 0, 0, 0);
      z = __builtin_amdgcn_mfma_f32_16x16x32_bf16(A2[1], B2[t][1], z, 0, 0, 0);
      acc2[t] = z;
    }

    // ---- messages + run-carry; flush only on dst change (group-uniform branch)
#pragma unroll
    for (int r = 0; r < 4; ++r) {
      const float C  = 0.5f * (__cosf(dd[r] * (F_PI / F_CUTOFF)) + 1.0f);
      const float m0 = bf2f(hp0[r] & 0xffffu) * ((acc2[0][r] + b2v[0]) * C);
      const float m1 = bf2f(hp0[r] >> 16)     * ((acc2[1][r] + b2v[1]) * C);
      const float m2 = bf2f(hp1[r] & 0xffffu) * ((acc2[2][r] + b2v[2]) * C);
      const float m3 = bf2f(hp1[r] >> 16)     * ((acc2[3][r] + b2v[3]) * C);
      if (dv[r] != run_dst) {
        if (run_dst >= 0) {
          unsigned short* ap = agg + (size_t)run_dst * NF + 2 * lo;
          const unsigned k0 = pkbf(c0, c1), k1 = pkbf(c2, c3);
          asm volatile("global_atomic_pk_add_bf16 %0, %1, off" :: "v"(ap), "v"(k0));
          asm volatile("global_atomic_pk_add_bf16 %0, %1, off" :: "v"(ap + 32), "v"(k1));
        }
        c0 = 0.f; c1 = 0.f; c2 = 0.f; c3 = 0.f;
        run_dst = dv[r];
      }
      c0 += m0; c1 += m1; c2 += m2; c3 += m3;
    }
  }
  // final flush
  if (run_dst >= 0) {
    unsigned short* ap = agg + (size_t)run_dst * NF + 2 * lo;
    const unsigned k0 = pkbf(c0, c1), k1 = pkbf(c2, c3);
    asm volatile("global_atomic_pk_add_bf16 %0, %1, off" :: "v"(ap), "v"(k0));
    asm volatile("global_atomic_pk_add_bf16 %0, %1, off" :: "v"(ap + 32), "v"(k1));
  }
}

// ---------------- kernel 3: out[n][d] = x[n][d] + relu(b[d] + agg[n,:] . lin2_w[d,:]) ----------------
__global__ __launch_bounds__(256) void k_out(
    const float* __restrict__ x, const unsigned short* __restrict__ agg,
    const float* __restrict__ w2, const float* __restrict__ b,
    float* __restrict__ out) {
  __shared__ __align__(16) float sw[DIM][NF + 4];
  __shared__ __align__(16) float sa[4][4][NF];
  for (int i = threadIdx.x; i < DIM * NF; i += 256)
    sw[i >> 6][i & 63] = w2[i];
  __syncthreads();
  const int wave = threadIdx.x >> 6, lane = threadIdx.x & 63;
  const float bias0 = b[lane], bias1 = b[lane + 64];
  const int nIter = NNODES / 4;
  for (int it = blockIdx.x * 4 + wave; it < nIter; it += gridDim.x * 4) {
    const int n0 = it * 4;
#pragma unroll
    for (int i = 0; i < 4; ++i)
      sa[wave][i][lane] = bf2f((unsigned)agg[(size_t)(n0 + i) * NF + lane]);
    float acc[8];
#pragma unroll
    for (int i = 0; i < 4; ++i) { acc[2 * i] = bias0; acc[2 * i + 1] = bias1; }
#pragma unroll
    for (int j4 = 0; j4 < NF / 4; ++j4) {
      const float4 wv0 = *(const float4*)&sw[lane][j4 * 4];
      const float4 wv1 = *(const float4*)&sw[lane + 64][j4 * 4];
#pragma unroll
      for (int i = 0; i < 4; ++i) {
        const float4 av = *(const float4*)&sa[wave][i][j4 * 4];
        acc[2 * i]     = fmaf(wv0.x, av.x, acc[2 * i]);
        acc[2 * i]     = fmaf(wv0.y, av.y, acc[2 * i]);
        acc[2 * i]     = fmaf(wv0.z, av.z, acc[2 * i]);
        acc[2 * i]     = fmaf(wv0.w, av.w, acc[2 * i]);
        acc[2 * i + 1] = fmaf(wv1.x, av.x, acc[2 * i + 1]);
        acc[2 * i + 1] = fmaf(wv1.y, av.y, acc[2 * i + 1]);
        acc[2 * i + 1] = fmaf(wv1.z, av.z, acc[2 * i + 1]);
        acc[2 * i + 1] = fmaf(wv1.w, av.w, acc[2 * i + 1]);
      }
    }
#pragma unroll
    for (int i = 0; i < 4; ++i) {
      const size_t base = (size_t)(n0 + i) * DIM;
      out[base + lane]      = x[base + lane]      + fmaxf(acc[2 * i],     0.f);
      out[base + 64 + lane] = x[base + 64 + lane] + fmaxf(acc[2 * i + 1], 0.f);
    }
  }
}

extern "C" void kernel_launch(void* const* d_in, const int* in_sizes, int n_in,
                              void* d_out, int out_size, void* d_ws, size_t ws_size,
                              hipStream_t stream) {
  const float* x   = (const float*)d_in[0];
  const int*   ei  = (const int*)  d_in[1];
  const float* ea  = (const float*)d_in[3];   // edge_attr == edge_weight (same dist)
  const float* l1w = (const float*)d_in[4];
  const float* l2w = (const float*)d_in[5];
  const float* l2b = (const float*)d_in[6];
  const float* e1w = (const float*)d_in[7];
  const float* e1b = (const float*)d_in[8];
  const float* e2w = (const float*)d_in[9];
  const float* e2b = (const float*)d_in[10];
  float* out = (float*)d_out;

  // ws carve: 26 MB (hbf 12.8 + agg 12.8 + counts 0.4)
  char* p = (char*)d_ws;
  unsigned short* hbf = (unsigned short*)p; p += (size_t)NNODES * NF * 2;
  unsigned short* agg = (unsigned short*)p; p += (size_t)NNODES * NF * 2;
  int* counts = (int*)p;                    p += (size_t)NNODES * 4;

  // sorted edge arrays live in d_out's dead space (overwritten by k_out at the end):
  // sd8 = {src,dist} 13.6 MB, sdst 6.8 MB  (d_out is 51.2 MB)
  int2* sd8  = (int2*)d_out;
  int*  sdst = (int*)((char*)d_out + (size_t)EPTOT * sizeof(int2));

  hipMemsetAsync(counts, 0, sizeof(int) * (size_t)NNODES, stream);
  hipMemsetAsync(agg, 0, sizeof(unsigned short) * (size_t)NNODES * NF, stream);

  k_lin1   <<<2048, 256, 0, stream>>>(x, l1w, hbf);
  k_hist   <<<(NEDGES + 255) / 256, 256, 0, stream>>>(ei, counts);
  k_scan   <<<1, 1024, 0, stream>>>(counts);
  k_reorder<<<(NEDGES + 255) / 256, 256, 0, stream>>>(ei, ea, counts, sd8, sdst);
  k_edge_mfma<<<NWAVES / 4, 256, 0, stream>>>(sd8, sdst, hbf, e1w, e1b, e2w, e2b, agg);
  k_out    <<<2048, 256, 0, stream>>>(x, agg, l2w, l2b, out);
}

// Round 6
// 467.936 us; speedup vs baseline: 1.4229x; 1.2999x over previous
//
#include <hip/hip_runtime.h>
#include <hip/hip_bf16.h>

#define NNODES 100000
#define NEDGES 1600000
#define DIM    128
#define NF     64
#define NG     50
#define H1P    20        // h1buf row stride in shorts (0 conflicts measured r3/r4)
#define EPG    52        // edges per 16-lane group chunk (13 iters x 4)
#define EPW    208       // edges per wave (4 groups)
#define NWAVES 8192      // 2048 blocks x 4 waves
#define EPTOT  1703936   // NWAVES * EPW  (>= NEDGES, OOB slots masked)

#define SC_CHUNK 1024
#define SC_NBLK  ((NNODES + SC_CHUNK - 1) / SC_CHUNK)   // 98

constexpr float F_CUTOFF = 5.0f;
constexpr float F_DELTA  = F_CUTOFF / (NG - 1);
constexpr float F_COEFF  = -0.5f / (F_DELTA * F_DELTA);
constexpr float F_PI     = 3.14159265358979323846f;

typedef __attribute__((ext_vector_type(8))) short short8v;
typedef __attribute__((ext_vector_type(4))) float f32x4;
typedef __attribute__((ext_vector_type(2))) int int2v;

__device__ inline unsigned short f2bf(float x) {
  __hip_bfloat16 h = __float2bfloat16(x);
  return *reinterpret_cast<unsigned short*>(&h);
}
__device__ inline unsigned pkbf(float a, float b) {
  float2 f2; f2.x = a; f2.y = b;
  __hip_bfloat162 h2 = __float22bfloat162_rn(f2);
  return *reinterpret_cast<unsigned*>(&h2);
}
__device__ inline float bf2f(unsigned int lo16) {
  return __uint_as_float(lo16 << 16);
}

// ---------------- kernel 1: h[n][f] = sum_k x[n][k] * lin1_w[f][k]  (bf16 out) ----------------
__global__ __launch_bounds__(256) void k_lin1(
    const float* __restrict__ x, const float* __restrict__ w1,
    unsigned short* __restrict__ h) {
  __shared__ __align__(16) float sw[NF][DIM + 4];
  for (int i = threadIdx.x; i < NF * DIM; i += 256)
    sw[i >> 7][i & 127] = w1[i];
  __syncthreads();
  const int wave = threadIdx.x >> 6, lane = threadIdx.x & 63;
  const int nIter = NNODES / 4;
  for (int it = blockIdx.x * 4 + wave; it < nIter; it += gridDim.x * 4) {
    const int n0 = it * 4;
    const float4* x0 = (const float4*)(x + (size_t)(n0 + 0) * DIM);
    const float4* x1 = (const float4*)(x + (size_t)(n0 + 1) * DIM);
    const float4* x2 = (const float4*)(x + (size_t)(n0 + 2) * DIM);
    const float4* x3 = (const float4*)(x + (size_t)(n0 + 3) * DIM);
    float a0 = 0.f, a1 = 0.f, a2 = 0.f, a3 = 0.f;
#pragma unroll 8
    for (int k4 = 0; k4 < DIM / 4; ++k4) {
      const float4 wv = *(const float4*)&sw[lane][k4 * 4];
      const float4 v0 = x0[k4], v1 = x1[k4], v2 = x2[k4], v3 = x3[k4];
      a0 = fmaf(v0.x, wv.x, a0); a0 = fmaf(v0.y, wv.y, a0);
      a0 = fmaf(v0.z, wv.z, a0); a0 = fmaf(v0.w, wv.w, a0);
      a1 = fmaf(v1.x, wv.x, a1); a1 = fmaf(v1.y, wv.y, a1);
      a1 = fmaf(v1.z, wv.z, a1); a1 = fmaf(v1.w, wv.w, a1);
      a2 = fmaf(v2.x, wv.x, a2); a2 = fmaf(v2.y, wv.y, a2);
      a2 = fmaf(v2.z, wv.z, a2); a2 = fmaf(v2.w, wv.w, a2);
      a3 = fmaf(v3.x, wv.x, a3); a3 = fmaf(v3.y, wv.y, a3);
      a3 = fmaf(v3.z, wv.z, a3); a3 = fmaf(v3.w, wv.w, a3);
    }
    h[(size_t)(n0 + 0) * NF + lane] = f2bf(a0);
    h[(size_t)(n0 + 1) * NF + lane] = f2bf(a1);
    h[(size_t)(n0 + 2) * NF + lane] = f2bf(a2);
    h[(size_t)(n0 + 3) * NF + lane] = f2bf(a3);
  }
}

// ---------------- histogram of dst ----------------
__global__ __launch_bounds__(256) void k_hist(
    const int* __restrict__ ei, int* __restrict__ counts) {
  const int e = blockIdx.x * 256 + threadIdx.x;
  if (e < NEDGES) atomicAdd(&counts[ei[NEDGES + e]], 1);
}

// ---------------- hierarchical exclusive scan: counts -> heads ----------------
// pass A: per-block (1024 elems) totals
__global__ __launch_bounds__(256) void k_scan_a(
    const int* __restrict__ counts, int* __restrict__ bsum) {
  __shared__ int red[256];
  const int t = threadIdx.x;
  const int i0 = blockIdx.x * SC_CHUNK + t * 4;
  int s = 0;
#pragma unroll
  for (int k = 0; k < 4; ++k) {
    const int i = i0 + k;
    if (i < NNODES) s += counts[i];
  }
  red[t] = s;
  __syncthreads();
  for (int off = 128; off > 0; off >>= 1) {
    if (t < off) red[t] += red[t + off];
    __syncthreads();
  }
  if (t == 0) bsum[blockIdx.x] = red[0];
}
// pass B: exclusive scan of the 98 block totals (single small block)
__global__ __launch_bounds__(128) void k_scan_b(int* __restrict__ bsum) {
  __shared__ int sb[128];
  const int t = threadIdx.x;
  const int v0 = (t < SC_NBLK) ? bsum[t] : 0;
  sb[t] = v0;
  __syncthreads();
  for (int off = 1; off < 128; off <<= 1) {
    const int xv = (t >= off) ? sb[t - off] : 0;
    __syncthreads();
    sb[t] += xv;
    __syncthreads();
  }
  if (t < SC_NBLK) bsum[t] = sb[t] - v0;   // exclusive
}
// pass C: local exclusive scan + block base -> heads
__global__ __launch_bounds__(256) void k_scan_c(
    const int* __restrict__ counts, const int* __restrict__ bsum,
    int* __restrict__ heads) {
  __shared__ int red[256];
  const int t = threadIdx.x;
  const int i0 = blockIdx.x * SC_CHUNK + t * 4;
  int v[4]; int s = 0;
#pragma unroll
  for (int k = 0; k < 4; ++k) {
    const int i = i0 + k;
    v[k] = (i < NNODES) ? counts[i] : 0;
    s += v[k];
  }
  red[t] = s;
  __syncthreads();
  const int my = s;
  for (int off = 1; off < 256; off <<= 1) {
    const int xv = (t >= off) ? red[t - off] : 0;
    __syncthreads();
    red[t] += xv;
    __syncthreads();
  }
  int run = bsum[blockIdx.x] + red[t] - my;
#pragma unroll
  for (int k = 0; k < 4; ++k) {
    const int i = i0 + k;
    if (i < NNODES) { heads[i] = run; run += v[k]; }
  }
}

// ---------------- reorder into dst-sorted arrays (living in d_out dead space) ----------------
__global__ __launch_bounds__(256) void k_reorder(
    const int* __restrict__ ei, const float* __restrict__ ea,
    int* __restrict__ heads, int2* __restrict__ sd8, int* __restrict__ sdst) {
  const int e = blockIdx.x * 256 + threadIdx.x;
  if (e < NEDGES) {
    const int dst = ei[NEDGES + e];
    const int pos = atomicAdd(&heads[dst], 1);
    int2 r; r.x = ei[e]; r.y = __float_as_int(ea[e]);
    sd8[pos] = r;
    sdst[pos] = dst;
  }
}

// ---------------- kernel 2: MFMA edge MLP, group-contiguous sorted chunks, carry-run flush ----------------
// Each 16-lane group owns EPG=52 consecutive sorted edges (4/iter x 13 iters); run sums are
// carried in registers across iterations and flushed with 2 pk-bf16 atomics per dst change.
// Phase2 tiles filter-pair permuted: lane holds filters (2lo,2lo+1) and (32+2lo,33+2lo).
// C/D layout (verified): col = lane&15, row = (lane>>4)*4 + reg.
__global__ __launch_bounds__(256) void k_edge_mfma(
    const int2* __restrict__ sd8, const int* __restrict__ sdst,
    const unsigned short* __restrict__ hbf,
    const float* __restrict__ w1, const float* __restrict__ b1,
    const float* __restrict__ w2, const float* __restrict__ b2,
    unsigned short* __restrict__ agg) {
  __shared__ __align__(16) unsigned short h1buf[4][NF][H1P];

  const int wave = threadIdx.x >> 6, lane = threadIdx.x & 63;
  const int lo = lane & 15, g = lane >> 4;

  // --- B1 fragments: B[k=gauss][n=f], f = t*16+lo, zero past NG
  short8v B1[4][2];
#pragma unroll
  for (int t = 0; t < 4; ++t)
#pragma unroll
    for (int s = 0; s < 2; ++s) {
      short8v f8;
#pragma unroll
      for (int i = 0; i < 8; ++i) {
        const int gg = s * 32 + g * 8 + i;
        const int f  = t * 16 + lo;
        f8[i] = (gg < NG) ? (short)f2bf(w1[f * NG + gg]) : (short)0;
      }
      B1[t][s] = f8;
    }
  // --- B2 fragments: output filter j = (t>>1)*32 + 2*lo + (t&1)
  short8v B2[4][2];
#pragma unroll
  for (int t = 0; t < 4; ++t)
#pragma unroll
    for (int s = 0; s < 2; ++s) {
      short8v f8;
#pragma unroll
      for (int i = 0; i < 8; ++i) {
        const int f_in = s * 32 + g * 8 + i;
        const int j = (t >> 1) * 32 + 2 * lo + (t & 1);
        f8[i] = (short)f2bf(w2[j * NF + f_in]);
      }
      B2[t][s] = f8;
    }
  float b1v[4], b2v[4];
#pragma unroll
  for (int t = 0; t < 4; ++t) {
    b1v[t] = b1[t * 16 + lo];
    b2v[t] = b2[(t >> 1) * 32 + 2 * lo + (t & 1)];
  }

  const float l2e  = F_COEFF * 1.44269504088896341f;
  const float goff = (float)(g * 8) * F_DELTA;

  const int wid   = blockIdx.x * 4 + wave;
  const int gbase = wid * EPW + g * EPG;                       // group's first slot
  const int lbase = wid * EPW + (lo >> 2) * EPG + (lo & 3);    // lane's A1-row slot base

  int run_dst = -1;
  float c0 = 0.f, c1 = 0.f, c2 = 0.f, c3 = 0.f;

  // 1-deep prefetch of broadcast loads
  int4 ra = *(const int4*)&sd8[gbase];
  int4 rb = *(const int4*)&sd8[gbase + 2];
  int4 dz = *(const int4*)&sdst[gbase];
  float dnx = __int_as_float(sd8[lbase].y);
  dnx = (lbase < NEDGES) ? dnx : 0.f;

#pragma unroll 1
  for (int it = 0; it < EPG / 4; ++it) {
    const int eg = gbase + it * 4;
    const int4 cra = ra, crb = rb, cdz = dz;
    const float d = dnx;
    {  // prefetch next (clamped: last iter re-loads itself, harmless)
      const int itn = (it + 1 < EPG / 4) ? it + 1 : it;
      const int egn = gbase + itn * 4;
      ra = *(const int4*)&sd8[egn];
      rb = *(const int4*)&sd8[egn + 2];
      dz = *(const int4*)&sdst[egn];
      const int lsn = lbase + itn * 4;
      float dn = __int_as_float(sd8[lsn].y);
      dnx = (lsn < NEDGES) ? dn : 0.f;
    }

    int   sv[4] = {cra.x, cra.z, crb.x, crb.z};
    float dd[4] = {__int_as_float(cra.y), __int_as_float(cra.w),
                   __int_as_float(crb.y), __int_as_float(crb.w)};
    int   dv[4] = {cdz.x, cdz.y, cdz.z, cdz.w};
#pragma unroll
    for (int r = 0; r < 4; ++r) {
      const bool val = (eg + r) < NEDGES;
      sv[r] = val ? sv[r] : 0;     // clamp gather address into hbf
      dv[r] = val ? dv[r] : -1;    // sentinel: never flushed
    }

    // ---- EARLY gathers (consumed at iteration tail, hidden under the MLP)
    unsigned hp0[4], hp1[4];
#pragma unroll
    for (int r = 0; r < 4; ++r) {
      const unsigned short* hs = hbf + (size_t)sv[r] * NF + 2 * lo;
      hp0[r] = *(const unsigned*)(hs);
      hp1[r] = *(const unsigned*)(hs + 32);
    }

    // ---- A1: gaussians straight into fragment layout (k>=NG columns are zero in B1)
    short8v A1[2];
#pragma unroll
    for (int s = 0; s < 2; ++s) {
      union { short8v v; unsigned u[4]; } au;
#pragma unroll
      for (int p = 0; p < 4; ++p) {
        const float off0 = goff + (float)(s * 32 + 2 * p) * F_DELTA;
        const float t0 = d - off0;
        const float t1 = d - (off0 + F_DELTA);
        au.u[p] = pkbf(exp2f(l2e * t0 * t0), exp2f(l2e * t1 * t1));
      }
      A1[s] = au.v;
    }

    // ---- phase 1 MFMA
    f32x4 acc1[4];
#pragma unroll
    for (int t = 0; t < 4; ++t) {
      f32x4 z = {0.f, 0.f, 0.f, 0.f};
      z = __builtin_amdgcn_mfma_f32_16x16x32_bf16(A1[0], B1[t][0], z, 0, 0, 0);
      z = __builtin_amdgcn_mfma_f32_16x16x32_bf16(A1[1], B1[t][1], z, 0, 0, 0);
      acc1[t] = z;
    }

    // ---- relu+bias, pack, LDS transpose store (f = t*16+lo, e = g*4..+3)
#pragma unroll
    for (int t = 0; t < 4; ++t) {
      const float v0 = fmaxf(acc1[t][0] + b1v[t], 0.f);
      const float v1 = fmaxf(acc1[t][1] + b1v[t], 0.f);
      const float v2 = fmaxf(acc1[t][2] + b1v[t], 0.f);
      const float v3 = fmaxf(acc1[t][3] + b1v[t], 0.f);
      int2v pk;
      pk[0] = (int)pkbf(v0, v1);
      pk[1] = (int)pkbf(v2, v3);
      *(int2v*)&h1buf[wave][t * 16 + lo][g * 4] = pk;
    }

    // ---- A2: column slice (e = lo, f_in = s*32+g*8+i)
    short8v A2[2];
#pragma unroll
    for (int s = 0; s < 2; ++s) {
      short8v f8;
#pragma unroll
      for (int i = 0; i < 8; ++i)
        f8[i] = (short)h1buf[wave][s * 32 + g * 8 + i][lo];
      A2[s] = f8;
    }

    // ---- phase 2 MFMA
    f32x4 acc2[4];
#pragma unroll
    for (int t = 0; t < 4; ++t) {
      f32x4 z = {0.f, 0.f, 0.f, 0.f};
      z = __builtin_amdgcn_mfma_f32_16x16x32_bf16(A2[0], B2[t][0], z, 0, 0, 0);
      z = __builtin_amdgcn_mfma_f32_16x16x32_bf16(A2[1], B2[t][1], z, 0, 0, 0);
      acc2[t] = z;
    }

    // ---- messages + run-carry; flush only on dst change (group-uniform branch)
#pragma unroll
    for (int r = 0; r < 4; ++r) {
      const float C  = 0.5f * (__cosf(dd[r] * (F_PI / F_CUTOFF)) + 1.0f);
      const float m0 = bf2f(hp0[r] & 0xffffu) * ((acc2[0][r] + b2v[0]) * C);
      const float m1 = bf2f(hp0[r] >> 16)     * ((acc2[1][r] + b2v[1]) * C);
      const float m2 = bf2f(hp1[r] & 0xffffu) * ((acc2[2][r] + b2v[2]) * C);
      const float m3 = bf2f(hp1[r] >> 16)     * ((acc2[3][r] + b2v[3]) * C);
      if (dv[r] != run_dst) {
        if (run_dst >= 0) {
          unsigned short* ap = agg + (size_t)run_dst * NF + 2 * lo;
          const unsigned k0 = pkbf(c0, c1), k1 = pkbf(c2, c3);
          asm volatile("global_atomic_pk_add_bf16 %0, %1, off" :: "v"(ap), "v"(k0));
          asm volatile("global_atomic_pk_add_bf16 %0, %1, off" :: "v"(ap + 32), "v"(k1));
        }
        c0 = 0.f; c1 = 0.f; c2 = 0.f; c3 = 0.f;
        run_dst = dv[r];
      }
      c0 += m0; c1 += m1; c2 += m2; c3 += m3;
    }
  }
  // final flush
  if (run_dst >= 0) {
    unsigned short* ap = agg + (size_t)run_dst * NF + 2 * lo;
    const unsigned k0 = pkbf(c0, c1), k1 = pkbf(c2, c3);
    asm volatile("global_atomic_pk_add_bf16 %0, %1, off" :: "v"(ap), "v"(k0));
    asm volatile("global_atomic_pk_add_bf16 %0, %1, off" :: "v"(ap + 32), "v"(k1));
  }
}

// ---------------- kernel 3: out[n][d] = x[n][d] + relu(b[d] + agg[n,:] . lin2_w[d,:]) ----------------
__global__ __launch_bounds__(256) void k_out(
    const float* __restrict__ x, const unsigned short* __restrict__ agg,
    const float* __restrict__ w2, const float* __restrict__ b,
    float* __restrict__ out) {
  __shared__ __align__(16) float sw[DIM][NF + 4];
  __shared__ __align__(16) float sa[4][4][NF];
  for (int i = threadIdx.x; i < DIM * NF; i += 256)
    sw[i >> 6][i & 63] = w2[i];
  __syncthreads();
  const int wave = threadIdx.x >> 6, lane = threadIdx.x & 63;
  const float bias0 = b[lane], bias1 = b[lane + 64];
  const int nIter = NNODES / 4;
  for (int it = blockIdx.x * 4 + wave; it < nIter; it += gridDim.x * 4) {
    const int n0 = it * 4;
#pragma unroll
    for (int i = 0; i < 4; ++i)
      sa[wave][i][lane] = bf2f((unsigned)agg[(size_t)(n0 + i) * NF + lane]);
    float acc[8];
#pragma unroll
    for (int i = 0; i < 4; ++i) { acc[2 * i] = bias0; acc[2 * i + 1] = bias1; }
#pragma unroll
    for (int j4 = 0; j4 < NF / 4; ++j4) {
      const float4 wv0 = *(const float4*)&sw[lane][j4 * 4];
      const float4 wv1 = *(const float4*)&sw[lane + 64][j4 * 4];
#pragma unroll
      for (int i = 0; i < 4; ++i) {
        const float4 av = *(const float4*)&sa[wave][i][j4 * 4];
        acc[2 * i]     = fmaf(wv0.x, av.x, acc[2 * i]);
        acc[2 * i]     = fmaf(wv0.y, av.y, acc[2 * i]);
        acc[2 * i]     = fmaf(wv0.z, av.z, acc[2 * i]);
        acc[2 * i]     = fmaf(wv0.w, av.w, acc[2 * i]);
        acc[2 * i + 1] = fmaf(wv1.x, av.x, acc[2 * i + 1]);
        acc[2 * i + 1] = fmaf(wv1.y, av.y, acc[2 * i + 1]);
        acc[2 * i + 1] = fmaf(wv1.z, av.z, acc[2 * i + 1]);
        acc[2 * i + 1] = fmaf(wv1.w, av.w, acc[2 * i + 1]);
      }
    }
#pragma unroll
    for (int i = 0; i < 4; ++i) {
      const size_t base = (size_t)(n0 + i) * DIM;
      out[base + lane]      = x[base + lane]      + fmaxf(acc[2 * i],     0.f);
      out[base + 64 + lane] = x[base + 64 + lane] + fmaxf(acc[2 * i + 1], 0.f);
    }
  }
}

extern "C" void kernel_launch(void* const* d_in, const int* in_sizes, int n_in,
                              void* d_out, int out_size, void* d_ws, size_t ws_size,
                              hipStream_t stream) {
  const float* x   = (const float*)d_in[0];
  const int*   ei  = (const int*)  d_in[1];
  const float* ea  = (const float*)d_in[3];   // edge_attr == edge_weight (same dist)
  const float* l1w = (const float*)d_in[4];
  const float* l2w = (const float*)d_in[5];
  const float* l2b = (const float*)d_in[6];
  const float* e1w = (const float*)d_in[7];
  const float* e1b = (const float*)d_in[8];
  const float* e2w = (const float*)d_in[9];
  const float* e2b = (const float*)d_in[10];
  float* out = (float*)d_out;

  // ws carve: ~27 MB (hbf 12.8 + agg 12.8 + counts 0.4 + heads 0.4 + bsum)
  char* p = (char*)d_ws;
  unsigned short* hbf = (unsigned short*)p; p += (size_t)NNODES * NF * 2;
  unsigned short* agg = (unsigned short*)p; p += (size_t)NNODES * NF * 2;
  int* counts = (int*)p;                    p += (size_t)NNODES * 4;
  int* heads  = (int*)p;                    p += (size_t)NNODES * 4;
  int* bsum   = (int*)p;                    p += 256 * 4;

  // sorted edge arrays live in d_out's dead space (overwritten by k_out at the end):
  // sd8 = {src,dist} 13.6 MB, sdst 6.8 MB  (d_out is 51.2 MB)
  int2* sd8  = (int2*)d_out;
  int*  sdst = (int*)((char*)d_out + (size_t)EPTOT * sizeof(int2));

  hipMemsetAsync(counts, 0, sizeof(int) * (size_t)NNODES, stream);
  hipMemsetAsync(agg, 0, sizeof(unsigned short) * (size_t)NNODES * NF, stream);

  k_lin1   <<<2048, 256, 0, stream>>>(x, l1w, hbf);
  k_hist   <<<(NEDGES + 255) / 256, 256, 0, stream>>>(ei, counts);
  k_scan_a <<<SC_NBLK, 256, 0, stream>>>(counts, bsum);
  k_scan_b <<<1, 128, 0, stream>>>(bsum);
  k_scan_c <<<SC_NBLK, 256, 0, stream>>>(counts, bsum, heads);
  k_reorder<<<(NEDGES + 255) / 256, 256, 0, stream>>>(ei, ea, heads, sd8, sdst);
  k_edge_mfma<<<NWAVES / 4, 256, 0, stream>>>(sd8, sdst, hbf, e1w, e1b, e2w, e2b, agg);
  k_out    <<<2048, 256, 0, stream>>>(x, agg, l2w, l2b, out);
}

// Round 7
// 433.751 us; speedup vs baseline: 1.5351x; 1.0788x over previous
//
#include <hip/hip_runtime.h>
#include <hip/hip_bf16.h>

#define NNODES 100000
#define NEDGES 1600000
#define DIM    128
#define NF     64
#define NG     50
#define H1P    20        // h1buf row stride in shorts (0 conflicts measured r3-r6)
#define EPG    52        // edges per 16-lane group chunk (13 iters x 4)
#define EPW    208       // edges per wave (4 groups)
#define NWAVES 8192      // 2048 blocks x 4 waves
#define EPTOT  1703936   // NWAVES * EPW  (>= NEDGES, OOB slots masked)

#define SC_CHUNK 1024
#define SC_NBLK  ((NNODES + SC_CHUNK - 1) / SC_CHUNK)   // 98

constexpr float F_CUTOFF = 5.0f;
constexpr float F_DELTA  = F_CUTOFF / (NG - 1);
constexpr float F_COEFF  = -0.5f / (F_DELTA * F_DELTA);
constexpr float F_PI     = 3.14159265358979323846f;

typedef __attribute__((ext_vector_type(8))) short short8v;
typedef __attribute__((ext_vector_type(4))) float f32x4;
typedef __attribute__((ext_vector_type(2))) int int2v;

__device__ inline unsigned short f2bf(float x) {
  __hip_bfloat16 h = __float2bfloat16(x);
  return *reinterpret_cast<unsigned short*>(&h);
}
__device__ inline unsigned pkbf(float a, float b) {
  float2 f2; f2.x = a; f2.y = b;
  __hip_bfloat162 h2 = __float22bfloat162_rn(f2);
  return *reinterpret_cast<unsigned*>(&h2);
}
__device__ inline float bf2f(unsigned int lo16) {
  return __uint_as_float(lo16 << 16);
}

// ---------------- kernel 1: h[n][f] = sum_k x[n][k] * lin1_w[f][k]  (bf16 out) ----------------
__global__ __launch_bounds__(256) void k_lin1(
    const float* __restrict__ x, const float* __restrict__ w1,
    unsigned short* __restrict__ h) {
  __shared__ __align__(16) float sw[NF][DIM + 4];
  for (int i = threadIdx.x; i < NF * DIM; i += 256)
    sw[i >> 7][i & 127] = w1[i];
  __syncthreads();
  const int wave = threadIdx.x >> 6, lane = threadIdx.x & 63;
  const int nIter = NNODES / 4;
  for (int it = blockIdx.x * 4 + wave; it < nIter; it += gridDim.x * 4) {
    const int n0 = it * 4;
    const float4* x0 = (const float4*)(x + (size_t)(n0 + 0) * DIM);
    const float4* x1 = (const float4*)(x + (size_t)(n0 + 1) * DIM);
    const float4* x2 = (const float4*)(x + (size_t)(n0 + 2) * DIM);
    const float4* x3 = (const float4*)(x + (size_t)(n0 + 3) * DIM);
    float a0 = 0.f, a1 = 0.f, a2 = 0.f, a3 = 0.f;
#pragma unroll 8
    for (int k4 = 0; k4 < DIM / 4; ++k4) {
      const float4 wv = *(const float4*)&sw[lane][k4 * 4];
      const float4 v0 = x0[k4], v1 = x1[k4], v2 = x2[k4], v3 = x3[k4];
      a0 = fmaf(v0.x, wv.x, a0); a0 = fmaf(v0.y, wv.y, a0);
      a0 = fmaf(v0.z, wv.z, a0); a0 = fmaf(v0.w, wv.w, a0);
      a1 = fmaf(v1.x, wv.x, a1); a1 = fmaf(v1.y, wv.y, a1);
      a1 = fmaf(v1.z, wv.z, a1); a1 = fmaf(v1.w, wv.w, a1);
      a2 = fmaf(v2.x, wv.x, a2); a2 = fmaf(v2.y, wv.y, a2);
      a2 = fmaf(v2.z, wv.z, a2); a2 = fmaf(v2.w, wv.w, a2);
      a3 = fmaf(v3.x, wv.x, a3); a3 = fmaf(v3.y, wv.y, a3);
      a3 = fmaf(v3.z, wv.z, a3); a3 = fmaf(v3.w, wv.w, a3);
    }
    h[(size_t)(n0 + 0) * NF + lane] = f2bf(a0);
    h[(size_t)(n0 + 1) * NF + lane] = f2bf(a1);
    h[(size_t)(n0 + 2) * NF + lane] = f2bf(a2);
    h[(size_t)(n0 + 3) * NF + lane] = f2bf(a3);
  }
}

// ---------------- histogram of dst ----------------
__global__ __launch_bounds__(256) void k_hist(
    const int* __restrict__ ei, int* __restrict__ counts) {
  const int e = blockIdx.x * 256 + threadIdx.x;
  if (e < NEDGES) atomicAdd(&counts[ei[NEDGES + e]], 1);
}

// ---------------- hierarchical exclusive scan: counts -> heads ----------------
__global__ __launch_bounds__(256) void k_scan_a(
    const int* __restrict__ counts, int* __restrict__ bsum) {
  __shared__ int red[256];
  const int t = threadIdx.x;
  const int i0 = blockIdx.x * SC_CHUNK + t * 4;
  int s = 0;
#pragma unroll
  for (int k = 0; k < 4; ++k) {
    const int i = i0 + k;
    if (i < NNODES) s += counts[i];
  }
  red[t] = s;
  __syncthreads();
  for (int off = 128; off > 0; off >>= 1) {
    if (t < off) red[t] += red[t + off];
    __syncthreads();
  }
  if (t == 0) bsum[blockIdx.x] = red[0];
}
__global__ __launch_bounds__(128) void k_scan_b(int* __restrict__ bsum) {
  __shared__ int sb[128];
  const int t = threadIdx.x;
  const int v0 = (t < SC_NBLK) ? bsum[t] : 0;
  sb[t] = v0;
  __syncthreads();
  for (int off = 1; off < 128; off <<= 1) {
    const int xv = (t >= off) ? sb[t - off] : 0;
    __syncthreads();
    sb[t] += xv;
    __syncthreads();
  }
  if (t < SC_NBLK) bsum[t] = sb[t] - v0;   // exclusive
}
__global__ __launch_bounds__(256) void k_scan_c(
    const int* __restrict__ counts, const int* __restrict__ bsum,
    int* __restrict__ heads) {
  __shared__ int red[256];
  const int t = threadIdx.x;
  const int i0 = blockIdx.x * SC_CHUNK + t * 4;
  int v[4]; int s = 0;
#pragma unroll
  for (int k = 0; k < 4; ++k) {
    const int i = i0 + k;
    v[k] = (i < NNODES) ? counts[i] : 0;
    s += v[k];
  }
  red[t] = s;
  __syncthreads();
  const int my = s;
  for (int off = 1; off < 256; off <<= 1) {
    const int xv = (t >= off) ? red[t - off] : 0;
    __syncthreads();
    red[t] += xv;
    __syncthreads();
  }
  int run = bsum[blockIdx.x] + red[t] - my;
#pragma unroll
  for (int k = 0; k < 4; ++k) {
    const int i = i0 + k;
    if (i < NNODES) { heads[i] = run; run += v[k]; }
  }
}

// ---------------- reorder into dst-sorted record array (one 16B scatter/edge) ----------------
__global__ __launch_bounds__(256) void k_reorder(
    const int* __restrict__ ei, const float* __restrict__ ea,
    int* __restrict__ heads, int4* __restrict__ srec) {
  const int e = blockIdx.x * 256 + threadIdx.x;
  if (e < NEDGES) {
    const int dst = ei[NEDGES + e];
    const int pos = atomicAdd(&heads[dst], 1);
    int4 r; r.x = ei[e]; r.y = __float_as_int(ea[e]); r.z = dst; r.w = 0;
    srec[pos] = r;
  }
}

// ---------------- kernel 2: MFMA edge MLP, group-contiguous sorted chunks, carry-run flush ----------------
// launch_bounds(256,2): VGPR cap 256 so B1/B2 weight fragments (64 VGPR) stay register-
// resident instead of being rematerialized per iteration (r6: VGPR=88 -> remat storm).
// Each 16-lane group owns EPG=52 consecutive sorted edges; run sums carried across iters,
// flushed with 2 pk-bf16 atomics per dst change.
// C/D layout (verified): col = lane&15, row = (lane>>4)*4 + reg.
__global__ __launch_bounds__(256, 2) void k_edge_mfma(
    const int4* __restrict__ srec, const unsigned short* __restrict__ hbf,
    const float* __restrict__ w1, const float* __restrict__ b1,
    const float* __restrict__ w2, const float* __restrict__ b2,
    unsigned short* __restrict__ agg) {
  __shared__ __align__(16) unsigned short h1buf[4][NF][H1P];

  const int wave = threadIdx.x >> 6, lane = threadIdx.x & 63;
  const int lo = lane & 15, g = lane >> 4;

  // --- B1 fragments: B[k=gauss][n=f], f = t*16+lo, zero past NG
  short8v B1[4][2];
#pragma unroll
  for (int t = 0; t < 4; ++t)
#pragma unroll
    for (int s = 0; s < 2; ++s) {
      short8v f8;
#pragma unroll
      for (int i = 0; i < 8; ++i) {
        const int gg = s * 32 + g * 8 + i;
        const int f  = t * 16 + lo;
        f8[i] = (gg < NG) ? (short)f2bf(w1[f * NG + gg]) : (short)0;
      }
      B1[t][s] = f8;
    }
  // --- B2 fragments: output filter j = (t>>1)*32 + 2*lo + (t&1)
  short8v B2[4][2];
#pragma unroll
  for (int t = 0; t < 4; ++t)
#pragma unroll
    for (int s = 0; s < 2; ++s) {
      short8v f8;
#pragma unroll
      for (int i = 0; i < 8; ++i) {
        const int f_in = s * 32 + g * 8 + i;
        const int j = (t >> 1) * 32 + 2 * lo + (t & 1);
        f8[i] = (short)f2bf(w2[j * NF + f_in]);
      }
      B2[t][s] = f8;
    }
  float b1v[4], b2v[4];
#pragma unroll
  for (int t = 0; t < 4; ++t) {
    b1v[t] = b1[t * 16 + lo];
    b2v[t] = b2[(t >> 1) * 32 + 2 * lo + (t & 1)];
  }

  const float l2e  = F_COEFF * 1.44269504088896341f;
  const float goff = (float)(g * 8) * F_DELTA;

  const int wid   = blockIdx.x * 4 + wave;
  const int gbase = wid * EPW + g * EPG;                       // group's first slot
  const int lbase = wid * EPW + (lo >> 2) * EPG + (lo & 3);    // lane's A1-row slot base

  int run_dst = -1;
  float c0 = 0.f, c1 = 0.f, c2 = 0.f, c3 = 0.f;

  // 1-deep prefetch of broadcast record loads
  int4 q0 = srec[gbase + 0];
  int4 q1 = srec[gbase + 1];
  int4 q2 = srec[gbase + 2];
  int4 q3 = srec[gbase + 3];
  float dnx = __int_as_float(srec[lbase].y);
  dnx = (lbase < NEDGES) ? dnx : 0.f;

#pragma unroll 1
  for (int it = 0; it < EPG / 4; ++it) {
    const int eg = gbase + it * 4;
    const int4 r0 = q0, r1 = q1, r2 = q2, r3 = q3;
    const float d = dnx;
    {  // prefetch next (clamped: last iter re-loads itself, harmless)
      const int itn = (it + 1 < EPG / 4) ? it + 1 : it;
      const int egn = gbase + itn * 4;
      q0 = srec[egn + 0]; q1 = srec[egn + 1];
      q2 = srec[egn + 2]; q3 = srec[egn + 3];
      const int lsn = lbase + itn * 4;
      float dn = __int_as_float(srec[lsn].y);
      dnx = (lsn < NEDGES) ? dn : 0.f;
    }

    int   sv[4] = {r0.x, r1.x, r2.x, r3.x};
    float dd[4] = {__int_as_float(r0.y), __int_as_float(r1.y),
                   __int_as_float(r2.y), __int_as_float(r3.y)};
    int   dv[4] = {r0.z, r1.z, r2.z, r3.z};
#pragma unroll
    for (int r = 0; r < 4; ++r) {
      const bool val = (eg + r) < NEDGES;
      sv[r] = val ? sv[r] : 0;     // clamp gather address into hbf
      dv[r] = val ? dv[r] : -1;    // sentinel: never flushed
    }

    // ---- EARLY gathers (consumed at iteration tail, hidden under the MLP)
    unsigned hp0[4], hp1[4];
#pragma unroll
    for (int r = 0; r < 4; ++r) {
      const unsigned short* hs = hbf + (size_t)sv[r] * NF + 2 * lo;
      hp0[r] = *(const unsigned*)(hs);
      hp1[r] = *(const unsigned*)(hs + 32);
    }

    // ---- A1: gaussians straight into fragment layout (k>=NG columns are zero in B1)
    short8v A1[2];
#pragma unroll
    for (int s = 0; s < 2; ++s) {
      union { short8v v; unsigned u[4]; } au;
#pragma unroll
      for (int p = 0; p < 4; ++p) {
        const float off0 = goff + (float)(s * 32 + 2 * p) * F_DELTA;
        const float t0 = d - off0;
        const float t1 = d - (off0 + F_DELTA);
        au.u[p] = pkbf(exp2f(l2e * t0 * t0), exp2f(l2e * t1 * t1));
      }
      A1[s] = au.v;
    }

    // ---- phase 1 MFMA
    f32x4 acc1[4];
#pragma unroll
    for (int t = 0; t < 4; ++t) {
      f32x4 z = {0.f, 0.f, 0.f, 0.f};
      z = __builtin_amdgcn_mfma_f32_16x16x32_bf16(A1[0], B1[t][0], z, 0, 0, 0);
      z = __builtin_amdgcn_mfma_f32_16x16x32_bf16(A1[1], B1[t][1], z, 0, 0, 0);
      acc1[t] = z;
    }

    // ---- relu+bias, pack, LDS transpose store (f = t*16+lo, e = g*4..+3)
#pragma unroll
    for (int t = 0; t < 4; ++t) {
      const float v0 = fmaxf(acc1[t][0] + b1v[t], 0.f);
      const float v1 = fmaxf(acc1[t][1] + b1v[t], 0.f);
      const float v2 = fmaxf(acc1[t][2] + b1v[t], 0.f);
      const float v3 = fmaxf(acc1[t][3] + b1v[t], 0.f);
      int2v pk;
      pk[0] = (int)pkbf(v0, v1);
      pk[1] = (int)pkbf(v2, v3);
      *(int2v*)&h1buf[wave][t * 16 + lo][g * 4] = pk;
    }

    // ---- A2: column slice (e = lo, f_in = s*32+g*8+i)
    short8v A2[2];
#pragma unroll
    for (int s = 0; s < 2; ++s) {
      short8v f8;
#pragma unroll
      for (int i = 0; i < 8; ++i)
        f8[i] = (short)h1buf[wave][s * 32 + g * 8 + i][lo];
      A2[s] = f8;
    }

    // ---- phase 2 MFMA
    f32x4 acc2[4];
#pragma unroll
    for (int t = 0; t < 4; ++t) {
      f32x4 z = {0.f, 0.f, 0.f, 0.f};
      z = __builtin_amdgcn_mfma_f32_16x16x32_bf16(A2[0], B2[t][0], z, 0, 0, 0);
      z = __builtin_amdgcn_mfma_f32_16x16x32_bf16(A2[1], B2[t][1], z, 0, 0, 0);
      acc2[t] = z;
    }

    // ---- messages + run-carry; flush only on dst change (group-uniform branch)
#pragma unroll
    for (int r = 0; r < 4; ++r) {
      const float C  = 0.5f * (__cosf(dd[r] * (F_PI / F_CUTOFF)) + 1.0f);
      const float m0 = bf2f(hp0[r] & 0xffffu) * ((acc2[0][r] + b2v[0]) * C);
      const float m1 = bf2f(hp0[r] >> 16)     * ((acc2[1][r] + b2v[1]) * C);
      const float m2 = bf2f(hp1[r] & 0xffffu) * ((acc2[2][r] + b2v[2]) * C);
      const float m3 = bf2f(hp1[r] >> 16)     * ((acc2[3][r] + b2v[3]) * C);
      if (dv[r] != run_dst) {
        if (run_dst >= 0) {
          unsigned short* ap = agg + (size_t)run_dst * NF + 2 * lo;
          const unsigned k0 = pkbf(c0, c1), k1 = pkbf(c2, c3);
          asm volatile("global_atomic_pk_add_bf16 %0, %1, off" :: "v"(ap), "v"(k0));
          asm volatile("global_atomic_pk_add_bf16 %0, %1, off" :: "v"(ap + 32), "v"(k1));
        }
        c0 = 0.f; c1 = 0.f; c2 = 0.f; c3 = 0.f;
        run_dst = dv[r];
      }
      c0 += m0; c1 += m1; c2 += m2; c3 += m3;
    }
  }
  // final flush
  if (run_dst >= 0) {
    unsigned short* ap = agg + (size_t)run_dst * NF + 2 * lo;
    const unsigned k0 = pkbf(c0, c1), k1 = pkbf(c2, c3);
    asm volatile("global_atomic_pk_add_bf16 %0, %1, off" :: "v"(ap), "v"(k0));
    asm volatile("global_atomic_pk_add_bf16 %0, %1, off" :: "v"(ap + 32), "v"(k1));
  }
}

// ---------------- kernel 3: out[n][d] = x[n][d] + relu(b[d] + agg[n,:] . lin2_w[d,:]) ----------------
__global__ __launch_bounds__(256) void k_out(
    const float* __restrict__ x, const unsigned short* __restrict__ agg,
    const float* __restrict__ w2, const float* __restrict__ b,
    float* __restrict__ out) {
  __shared__ __align__(16) float sw[DIM][NF + 4];
  __shared__ __align__(16) float sa[4][4][NF];
  for (int i = threadIdx.x; i < DIM * NF; i += 256)
    sw[i >> 6][i & 63] = w2[i];
  __syncthreads();
  const int wave = threadIdx.x >> 6, lane = threadIdx.x & 63;
  const float bias0 = b[lane], bias1 = b[lane + 64];
  const int nIter = NNODES / 4;
  for (int it = blockIdx.x * 4 + wave; it < nIter; it += gridDim.x * 4) {
    const int n0 = it * 4;
#pragma unroll
    for (int i = 0; i < 4; ++i)
      sa[wave][i][lane] = bf2f((unsigned)agg[(size_t)(n0 + i) * NF + lane]);
    float acc[8];
#pragma unroll
    for (int i = 0; i < 4; ++i) { acc[2 * i] = bias0; acc[2 * i + 1] = bias1; }
#pragma unroll
    for (int j4 = 0; j4 < NF / 4; ++j4) {
      const float4 wv0 = *(const float4*)&sw[lane][j4 * 4];
      const float4 wv1 = *(const float4*)&sw[lane + 64][j4 * 4];
#pragma unroll
      for (int i = 0; i < 4; ++i) {
        const float4 av = *(const float4*)&sa[wave][i][j4 * 4];
        acc[2 * i]     = fmaf(wv0.x, av.x, acc[2 * i]);
        acc[2 * i]     = fmaf(wv0.y, av.y, acc[2 * i]);
        acc[2 * i]     = fmaf(wv0.z, av.z, acc[2 * i]);
        acc[2 * i]     = fmaf(wv0.w, av.w, acc[2 * i]);
        acc[2 * i + 1] = fmaf(wv1.x, av.x, acc[2 * i + 1]);
        acc[2 * i + 1] = fmaf(wv1.y, av.y, acc[2 * i + 1]);
        acc[2 * i + 1] = fmaf(wv1.z, av.z, acc[2 * i + 1]);
        acc[2 * i + 1] = fmaf(wv1.w, av.w, acc[2 * i + 1]);
      }
    }
#pragma unroll
    for (int i = 0; i < 4; ++i) {
      const size_t base = (size_t)(n0 + i) * DIM;
      out[base + lane]      = x[base + lane]      + fmaxf(acc[2 * i],     0.f);
      out[base + 64 + lane] = x[base + 64 + lane] + fmaxf(acc[2 * i + 1], 0.f);
    }
  }
}

extern "C" void kernel_launch(void* const* d_in, const int* in_sizes, int n_in,
                              void* d_out, int out_size, void* d_ws, size_t ws_size,
                              hipStream_t stream) {
  const float* x   = (const float*)d_in[0];
  const int*   ei  = (const int*)  d_in[1];
  const float* ea  = (const float*)d_in[3];   // edge_attr == edge_weight (same dist)
  const float* l1w = (const float*)d_in[4];
  const float* l2w = (const float*)d_in[5];
  const float* l2b = (const float*)d_in[6];
  const float* e1w = (const float*)d_in[7];
  const float* e1b = (const float*)d_in[8];
  const float* e2w = (const float*)d_in[9];
  const float* e2b = (const float*)d_in[10];
  float* out = (float*)d_out;

  // ws carve: ~27 MB (hbf 12.8 + agg 12.8 + counts 0.4 + heads 0.4 + bsum)
  char* p = (char*)d_ws;
  unsigned short* hbf = (unsigned short*)p; p += (size_t)NNODES * NF * 2;
  unsigned short* agg = (unsigned short*)p; p += (size_t)NNODES * NF * 2;
  int* counts = (int*)p;                    p += (size_t)NNODES * 4;
  int* heads  = (int*)p;                    p += (size_t)NNODES * 4;
  int* bsum   = (int*)p;                    p += 256 * 4;

  // sorted edge records live in d_out's dead space (overwritten by k_out at the end):
  // srec = {src, dist, dst, 0} int4, EPTOT*16B = 27.3 MB  (d_out is 51.2 MB)
  int4* srec = (int4*)d_out;

  hipMemsetAsync(counts, 0, sizeof(int) * (size_t)NNODES, stream);
  hipMemsetAsync(agg, 0, sizeof(unsigned short) * (size_t)NNODES * NF, stream);

  k_lin1   <<<2048, 256, 0, stream>>>(x, l1w, hbf);
  k_hist   <<<(NEDGES + 255) / 256, 256, 0, stream>>>(ei, counts);
  k_scan_a <<<SC_NBLK, 256, 0, stream>>>(counts, bsum);
  k_scan_b <<<1, 128, 0, stream>>>(bsum);
  k_scan_c <<<SC_NBLK, 256, 0, stream>>>(counts, bsum, heads);
  k_reorder<<<(NEDGES + 255) / 256, 256, 0, stream>>>(ei, ea, heads, srec);
  k_edge_mfma<<<NWAVES / 4, 256, 0, stream>>>(srec, hbf, e1w, e1b, e2w, e2b, agg);
  k_out    <<<2048, 256, 0, stream>>>(x, agg, l2w, l2b, out);
}

// Round 8
// 326.528 us; speedup vs baseline: 2.0391x; 1.3284x over previous
//
#include <hip/hip_runtime.h>
#include <hip/hip_bf16.h>

#define NNODES 100000
#define NEDGES 1600000
#define DIM    128
#define NF     64
#define NG     50
#define H1P    20        // h1buf row stride in shorts (0 conflicts measured r3-r7)
#define EPG    52        // edges per 16-lane group chunk (13 iters x 4)
#define EPW    208       // edges per wave (4 groups)
#define NWAVES 8192      // 2048 blocks x 4 waves
#define EPTOT  1703936   // NWAVES * EPW  (>= NEDGES, OOB slots masked)

#define BSH    9                         // bucket = dst >> 9 (512 nodes/bucket)
#define NB     ((NNODES + 511) >> 9)     // 196 buckets
#define CHK    8192                      // edges per block in bucket passes
#define NCHK   ((NEDGES + CHK - 1) / CHK)  // 196 blocks

constexpr float F_CUTOFF = 5.0f;
constexpr float F_DELTA  = F_CUTOFF / (NG - 1);
constexpr float F_COEFF  = -0.5f / (F_DELTA * F_DELTA);
constexpr float F_PI     = 3.14159265358979323846f;

typedef __attribute__((ext_vector_type(8))) short short8v;
typedef __attribute__((ext_vector_type(4))) float f32x4;
typedef __attribute__((ext_vector_type(2))) int int2v;

__device__ inline unsigned short f2bf(float x) {
  __hip_bfloat16 h = __float2bfloat16(x);
  return *reinterpret_cast<unsigned short*>(&h);
}
__device__ inline unsigned pkbf(float a, float b) {
  float2 f2; f2.x = a; f2.y = b;
  __hip_bfloat162 h2 = __float22bfloat162_rn(f2);
  return *reinterpret_cast<unsigned*>(&h2);
}
__device__ inline float bf2f(unsigned int lo16) {
  return __uint_as_float(lo16 << 16);
}

// ---------------- kernel 1: h[n][f] = sum_k x[n][k] * lin1_w[f][k]  (bf16 out) ----------------
__global__ __launch_bounds__(256) void k_lin1(
    const float* __restrict__ x, const float* __restrict__ w1,
    unsigned short* __restrict__ h) {
  __shared__ __align__(16) float sw[NF][DIM + 4];
  for (int i = threadIdx.x; i < NF * DIM; i += 256)
    sw[i >> 7][i & 127] = w1[i];
  __syncthreads();
  const int wave = threadIdx.x >> 6, lane = threadIdx.x & 63;
  const int nIter = NNODES / 4;
  for (int it = blockIdx.x * 4 + wave; it < nIter; it += gridDim.x * 4) {
    const int n0 = it * 4;
    const float4* x0 = (const float4*)(x + (size_t)(n0 + 0) * DIM);
    const float4* x1 = (const float4*)(x + (size_t)(n0 + 1) * DIM);
    const float4* x2 = (const float4*)(x + (size_t)(n0 + 2) * DIM);
    const float4* x3 = (const float4*)(x + (size_t)(n0 + 3) * DIM);
    float a0 = 0.f, a1 = 0.f, a2 = 0.f, a3 = 0.f;
#pragma unroll 8
    for (int k4 = 0; k4 < DIM / 4; ++k4) {
      const float4 wv = *(const float4*)&sw[lane][k4 * 4];
      const float4 v0 = x0[k4], v1 = x1[k4], v2 = x2[k4], v3 = x3[k4];
      a0 = fmaf(v0.x, wv.x, a0); a0 = fmaf(v0.y, wv.y, a0);
      a0 = fmaf(v0.z, wv.z, a0); a0 = fmaf(v0.w, wv.w, a0);
      a1 = fmaf(v1.x, wv.x, a1); a1 = fmaf(v1.y, wv.y, a1);
      a1 = fmaf(v1.z, wv.z, a1); a1 = fmaf(v1.w, wv.w, a1);
      a2 = fmaf(v2.x, wv.x, a2); a2 = fmaf(v2.y, wv.y, a2);
      a2 = fmaf(v2.z, wv.z, a2); a2 = fmaf(v2.w, wv.w, a2);
      a3 = fmaf(v3.x, wv.x, a3); a3 = fmaf(v3.y, wv.y, a3);
      a3 = fmaf(v3.z, wv.z, a3); a3 = fmaf(v3.w, wv.w, a3);
    }
    h[(size_t)(n0 + 0) * NF + lane] = f2bf(a0);
    h[(size_t)(n0 + 1) * NF + lane] = f2bf(a1);
    h[(size_t)(n0 + 2) * NF + lane] = f2bf(a2);
    h[(size_t)(n0 + 3) * NF + lane] = f2bf(a3);
  }
}

// ---------------- bucket histogram: per-block LDS counts, 196 global atomics/block ----------------
__global__ __launch_bounds__(256) void k_bhist(
    const int* __restrict__ ei, int* __restrict__ gcnt) {
  __shared__ int lcnt[NB];
  for (int i = threadIdx.x; i < NB; i += 256) lcnt[i] = 0;
  __syncthreads();
  const int base = blockIdx.x * CHK;
  for (int i = threadIdx.x; i < CHK; i += 256) {
    const int e = base + i;
    if (e < NEDGES) atomicAdd(&lcnt[ei[NEDGES + e] >> BSH], 1);
  }
  __syncthreads();
  for (int i = threadIdx.x; i < NB; i += 256)
    if (lcnt[i]) atomicAdd(&gcnt[i], lcnt[i]);
}

// ---------------- scan 196 bucket totals -> boff[0..NB] (exclusive, boff[NB]=E) + cursor copy ----------------
__global__ __launch_bounds__(256) void k_bscan(
    const int* __restrict__ gcnt, int* __restrict__ boff, int* __restrict__ bcur) {
  __shared__ int sb[256];
  const int t = threadIdx.x;
  const int v = (t < NB) ? gcnt[t] : 0;
  sb[t] = v;
  __syncthreads();
  for (int off = 1; off < 256; off <<= 1) {
    const int xv = (t >= off) ? sb[t - off] : 0;
    __syncthreads();
    sb[t] += xv;
    __syncthreads();
  }
  if (t <= NB) {
    const int ex = sb[t] - v;
    boff[t] = ex;
    if (t < NB) bcur[t] = ex;
  }
}

// ---------------- pass 1: bucket-scatter with per-(block,bucket) contiguous chunks ----------------
__global__ __launch_bounds__(256) void k_bscatter(
    const int* __restrict__ ei, const float* __restrict__ ea,
    int* __restrict__ bcur, int2* __restrict__ sd8S, int* __restrict__ sdstS) {
  __shared__ int lcnt[NB];
  __shared__ int lcur[NB];
  for (int i = threadIdx.x; i < NB; i += 256) lcnt[i] = 0;
  __syncthreads();
  const int base = blockIdx.x * CHK;
  // pass A: local bucket counts
  for (int i = threadIdx.x; i < CHK; i += 256) {
    const int e = base + i;
    if (e < NEDGES) atomicAdd(&lcnt[ei[NEDGES + e] >> BSH], 1);
  }
  __syncthreads();
  // reserve contiguous chunk per bucket
  for (int i = threadIdx.x; i < NB; i += 256)
    lcur[i] = lcnt[i] ? atomicAdd(&bcur[i], lcnt[i]) : 0;
  __syncthreads();
  // pass B: place edges at LDS-assigned positions (dense per-bucket chunks)
  for (int i = threadIdx.x; i < CHK; i += 256) {
    const int e = base + i;
    if (e < NEDGES) {
      const int dst = ei[NEDGES + e];
      const int pos = atomicAdd(&lcur[dst >> BSH], 1);
      int2 r; r.x = ei[e]; r.y = __float_as_int(ea[e]);
      sd8S[pos]  = r;
      sdstS[pos] = dst;
    }
  }
}

// ---------------- pass 2: per-bucket LDS counting sort -> final dst-sorted records ----------------
__global__ __launch_bounds__(256) void k_bsort(
    const int2* __restrict__ sd8S, const int* __restrict__ sdstS,
    const int* __restrict__ boff, int4* __restrict__ srec) {
  __shared__ int cnt[512];
  __shared__ int red[256];
  const int b = blockIdx.x;
  const int t = threadIdx.x;
  const int s0 = boff[b], s1 = boff[b + 1];
  const int nodeBase = b << BSH;
  cnt[t] = 0; cnt[t + 256] = 0;
  __syncthreads();
  // count per-node occurrences
  for (int i = s0 + t; i < s1; i += 256)
    atomicAdd(&cnt[sdstS[i] - nodeBase], 1);
  __syncthreads();
  // exclusive scan of 512 counts (2 per thread)
  const int v0 = cnt[2 * t], v1 = cnt[2 * t + 1];
  const int sum2 = v0 + v1;
  red[t] = sum2;
  __syncthreads();
  for (int off = 1; off < 256; off <<= 1) {
    const int xv = (t >= off) ? red[t - off] : 0;
    __syncthreads();
    red[t] += xv;
    __syncthreads();
  }
  const int ex = s0 + red[t] - sum2;   // global final base for node 2t
  cnt[2 * t]     = ex;                 // reuse cnt[] as cursors
  cnt[2 * t + 1] = ex + v0;
  __syncthreads();
  // place records
  for (int i = s0 + t; i < s1; i += 256) {
    const int2 r8 = sd8S[i];
    const int dst = sdstS[i];
    const int p = atomicAdd(&cnt[dst - nodeBase], 1);
    int4 r; r.x = r8.x; r.y = r8.y; r.z = dst; r.w = 0;
    srec[p] = r;
  }
}

// ---------------- kernel 2: MFMA edge MLP, group-contiguous sorted chunks, carry-run flush ----------------
// launch_bounds(256,2): VGPR cap 256 so B1/B2 weight fragments stay register-resident.
// Each 16-lane group owns EPG=52 consecutive sorted edges; run sums carried across iters,
// flushed with 2 pk-bf16 atomics per dst change.
// C/D layout (verified): col = lane&15, row = (lane>>4)*4 + reg.
__global__ __launch_bounds__(256, 2) void k_edge_mfma(
    const int4* __restrict__ srec, const unsigned short* __restrict__ hbf,
    const float* __restrict__ w1, const float* __restrict__ b1,
    const float* __restrict__ w2, const float* __restrict__ b2,
    unsigned short* __restrict__ agg) {
  __shared__ __align__(16) unsigned short h1buf[4][NF][H1P];

  const int wave = threadIdx.x >> 6, lane = threadIdx.x & 63;
  const int lo = lane & 15, g = lane >> 4;

  // --- B1 fragments: B[k=gauss][n=f], f = t*16+lo, zero past NG
  short8v B1[4][2];
#pragma unroll
  for (int t = 0; t < 4; ++t)
#pragma unroll
    for (int s = 0; s < 2; ++s) {
      short8v f8;
#pragma unroll
      for (int i = 0; i < 8; ++i) {
        const int gg = s * 32 + g * 8 + i;
        const int f  = t * 16 + lo;
        f8[i] = (gg < NG) ? (short)f2bf(w1[f * NG + gg]) : (short)0;
      }
      B1[t][s] = f8;
    }
  // --- B2 fragments: output filter j = (t>>1)*32 + 2*lo + (t&1)
  short8v B2[4][2];
#pragma unroll
  for (int t = 0; t < 4; ++t)
#pragma unroll
    for (int s = 0; s < 2; ++s) {
      short8v f8;
#pragma unroll
      for (int i = 0; i < 8; ++i) {
        const int f_in = s * 32 + g * 8 + i;
        const int j = (t >> 1) * 32 + 2 * lo + (t & 1);
        f8[i] = (short)f2bf(w2[j * NF + f_in]);
      }
      B2[t][s] = f8;
    }
  float b1v[4], b2v[4];
#pragma unroll
  for (int t = 0; t < 4; ++t) {
    b1v[t] = b1[t * 16 + lo];
    b2v[t] = b2[(t >> 1) * 32 + 2 * lo + (t & 1)];
  }

  const float l2e  = F_COEFF * 1.44269504088896341f;
  const float goff = (float)(g * 8) * F_DELTA;

  const int wid   = blockIdx.x * 4 + wave;
  const int gbase = wid * EPW + g * EPG;                       // group's first slot
  const int lbase = wid * EPW + (lo >> 2) * EPG + (lo & 3);    // lane's A1-row slot base

  int run_dst = -1;
  float c0 = 0.f, c1 = 0.f, c2 = 0.f, c3 = 0.f;

  // 1-deep prefetch of broadcast record loads
  int4 q0 = srec[gbase + 0];
  int4 q1 = srec[gbase + 1];
  int4 q2 = srec[gbase + 2];
  int4 q3 = srec[gbase + 3];
  float dnx = __int_as_float(srec[lbase].y);
  dnx = (lbase < NEDGES) ? dnx : 0.f;

#pragma unroll 1
  for (int it = 0; it < EPG / 4; ++it) {
    const int eg = gbase + it * 4;
    const int4 r0 = q0, r1 = q1, r2 = q2, r3 = q3;
    const float d = dnx;
    {  // prefetch next (clamped: last iter re-loads itself, harmless)
      const int itn = (it + 1 < EPG / 4) ? it + 1 : it;
      const int egn = gbase + itn * 4;
      q0 = srec[egn + 0]; q1 = srec[egn + 1];
      q2 = srec[egn + 2]; q3 = srec[egn + 3];
      const int lsn = lbase + itn * 4;
      float dn = __int_as_float(srec[lsn].y);
      dnx = (lsn < NEDGES) ? dn : 0.f;
    }

    int   sv[4] = {r0.x, r1.x, r2.x, r3.x};
    float dd[4] = {__int_as_float(r0.y), __int_as_float(r1.y),
                   __int_as_float(r2.y), __int_as_float(r3.y)};
    int   dv[4] = {r0.z, r1.z, r2.z, r3.z};
#pragma unroll
    for (int r = 0; r < 4; ++r) {
      const bool val = (eg + r) < NEDGES;
      sv[r] = val ? sv[r] : 0;     // clamp gather address into hbf
      dv[r] = val ? dv[r] : -1;    // sentinel: never flushed
    }

    // ---- EARLY gathers (consumed at iteration tail, hidden under the MLP)
    unsigned hp0[4], hp1[4];
#pragma unroll
    for (int r = 0; r < 4; ++r) {
      const unsigned short* hs = hbf + (size_t)sv[r] * NF + 2 * lo;
      hp0[r] = *(const unsigned*)(hs);
      hp1[r] = *(const unsigned*)(hs + 32);
    }

    // ---- A1: gaussians straight into fragment layout (k>=NG columns are zero in B1)
    short8v A1[2];
#pragma unroll
    for (int s = 0; s < 2; ++s) {
      union { short8v v; unsigned u[4]; } au;
#pragma unroll
      for (int p = 0; p < 4; ++p) {
        const float off0 = goff + (float)(s * 32 + 2 * p) * F_DELTA;
        const float t0 = d - off0;
        const float t1 = d - (off0 + F_DELTA);
        au.u[p] = pkbf(exp2f(l2e * t0 * t0), exp2f(l2e * t1 * t1));
      }
      A1[s] = au.v;
    }

    // ---- phase 1 MFMA
    f32x4 acc1[4];
#pragma unroll
    for (int t = 0; t < 4; ++t) {
      f32x4 z = {0.f, 0.f, 0.f, 0.f};
      z = __builtin_amdgcn_mfma_f32_16x16x32_bf16(A1[0], B1[t][0], z, 0, 0, 0);
      z = __builtin_amdgcn_mfma_f32_16x16x32_bf16(A1[1], B1[t][1], z, 0, 0, 0);
      acc1[t] = z;
    }

    // ---- relu+bias, pack, LDS transpose store (f = t*16+lo, e = g*4..+3)
#pragma unroll
    for (int t = 0; t < 4; ++t) {
      const float v0 = fmaxf(acc1[t][0] + b1v[t], 0.f);
      const float v1 = fmaxf(acc1[t][1] + b1v[t], 0.f);
      const float v2 = fmaxf(acc1[t][2] + b1v[t], 0.f);
      const float v3 = fmaxf(acc1[t][3] + b1v[t], 0.f);
      int2v pk;
      pk[0] = (int)pkbf(v0, v1);
      pk[1] = (int)pkbf(v2, v3);
      *(int2v*)&h1buf[wave][t * 16 + lo][g * 4] = pk;
    }

    // ---- A2: column slice (e = lo, f_in = s*32+g*8+i)
    short8v A2[2];
#pragma unroll
    for (int s = 0; s < 2; ++s) {
      short8v f8;
#pragma unroll
      for (int i = 0; i < 8; ++i)
        f8[i] = (short)h1buf[wave][s * 32 + g * 8 + i][lo];
      A2[s] = f8;
    }

    // ---- phase 2 MFMA
    f32x4 acc2[4];
#pragma unroll
    for (int t = 0; t < 4; ++t) {
      f32x4 z = {0.f, 0.f, 0.f, 0.f};
      z = __builtin_amdgcn_mfma_f32_16x16x32_bf16(A2[0], B2[t][0], z, 0, 0, 0);
      z = __builtin_amdgcn_mfma_f32_16x16x32_bf16(A2[1], B2[t][1], z, 0, 0, 0);
      acc2[t] = z;
    }

    // ---- messages + run-carry; flush only on dst change (group-uniform branch)
#pragma unroll
    for (int r = 0; r < 4; ++r) {
      const float C  = 0.5f * (__cosf(dd[r] * (F_PI / F_CUTOFF)) + 1.0f);
      const float m0 = bf2f(hp0[r] & 0xffffu) * ((acc2[0][r] + b2v[0]) * C);
      const float m1 = bf2f(hp0[r] >> 16)     * ((acc2[1][r] + b2v[1]) * C);
      const float m2 = bf2f(hp1[r] & 0xffffu) * ((acc2[2][r] + b2v[2]) * C);
      const float m3 = bf2f(hp1[r] >> 16)     * ((acc2[3][r] + b2v[3]) * C);
      if (dv[r] != run_dst) {
        if (run_dst >= 0) {
          unsigned short* ap = agg + (size_t)run_dst * NF + 2 * lo;
          const unsigned k0 = pkbf(c0, c1), k1 = pkbf(c2, c3);
          asm volatile("global_atomic_pk_add_bf16 %0, %1, off" :: "v"(ap), "v"(k0));
          asm volatile("global_atomic_pk_add_bf16 %0, %1, off" :: "v"(ap + 32), "v"(k1));
        }
        c0 = 0.f; c1 = 0.f; c2 = 0.f; c3 = 0.f;
        run_dst = dv[r];
      }
      c0 += m0; c1 += m1; c2 += m2; c3 += m3;
    }
  }
  // final flush
  if (run_dst >= 0) {
    unsigned short* ap = agg + (size_t)run_dst * NF + 2 * lo;
    const unsigned k0 = pkbf(c0, c1), k1 = pkbf(c2, c3);
    asm volatile("global_atomic_pk_add_bf16 %0, %1, off" :: "v"(ap), "v"(k0));
    asm volatile("global_atomic_pk_add_bf16 %0, %1, off" :: "v"(ap + 32), "v"(k1));
  }
}

// ---------------- kernel 3: out[n][d] = x[n][d] + relu(b[d] + agg[n,:] . lin2_w[d,:]) ----------------
__global__ __launch_bounds__(256) void k_out(
    const float* __restrict__ x, const unsigned short* __restrict__ agg,
    const float* __restrict__ w2, const float* __restrict__ b,
    float* __restrict__ out) {
  __shared__ __align__(16) float sw[DIM][NF + 4];
  __shared__ __align__(16) float sa[4][4][NF];
  for (int i = threadIdx.x; i < DIM * NF; i += 256)
    sw[i >> 6][i & 63] = w2[i];
  __syncthreads();
  const int wave = threadIdx.x >> 6, lane = threadIdx.x & 63;
  const float bias0 = b[lane], bias1 = b[lane + 64];
  const int nIter = NNODES / 4;
  for (int it = blockIdx.x * 4 + wave; it < nIter; it += gridDim.x * 4) {
    const int n0 = it * 4;
#pragma unroll
    for (int i = 0; i < 4; ++i)
      sa[wave][i][lane] = bf2f((unsigned)agg[(size_t)(n0 + i) * NF + lane]);
    float acc[8];
#pragma unroll
    for (int i = 0; i < 4; ++i) { acc[2 * i] = bias0; acc[2 * i + 1] = bias1; }
#pragma unroll
    for (int j4 = 0; j4 < NF / 4; ++j4) {
      const float4 wv0 = *(const float4*)&sw[lane][j4 * 4];
      const float4 wv1 = *(const float4*)&sw[lane + 64][j4 * 4];
#pragma unroll
      for (int i = 0; i < 4; ++i) {
        const float4 av = *(const float4*)&sa[wave][i][j4 * 4];
        acc[2 * i]     = fmaf(wv0.x, av.x, acc[2 * i]);
        acc[2 * i]     = fmaf(wv0.y, av.y, acc[2 * i]);
        acc[2 * i]     = fmaf(wv0.z, av.z, acc[2 * i]);
        acc[2 * i]     = fmaf(wv0.w, av.w, acc[2 * i]);
        acc[2 * i + 1] = fmaf(wv1.x, av.x, acc[2 * i + 1]);
        acc[2 * i + 1] = fmaf(wv1.y, av.y, acc[2 * i + 1]);
        acc[2 * i + 1] = fmaf(wv1.z, av.z, acc[2 * i + 1]);
        acc[2 * i + 1] = fmaf(wv1.w, av.w, acc[2 * i + 1]);
      }
    }
#pragma unroll
    for (int i = 0; i < 4; ++i) {
      const size_t base = (size_t)(n0 + i) * DIM;
      out[base + lane]      = x[base + lane]      + fmaxf(acc[2 * i],     0.f);
      out[base + 64 + lane] = x[base + 64 + lane] + fmaxf(acc[2 * i + 1], 0.f);
    }
  }
}

extern "C" void kernel_launch(void* const* d_in, const int* in_sizes, int n_in,
                              void* d_out, int out_size, void* d_ws, size_t ws_size,
                              hipStream_t stream) {
  const float* x   = (const float*)d_in[0];
  const int*   ei  = (const int*)  d_in[1];
  const float* ea  = (const float*)d_in[3];   // edge_attr == edge_weight (same dist)
  const float* l1w = (const float*)d_in[4];
  const float* l2w = (const float*)d_in[5];
  const float* l2b = (const float*)d_in[6];
  const float* e1w = (const float*)d_in[7];
  const float* e1b = (const float*)d_in[8];
  const float* e2w = (const float*)d_in[9];
  const float* e2b = (const float*)d_in[10];
  float* out = (float*)d_out;

  // ws carve: hbf 12.8 + agg 12.8 + staging sd8S 12.8 + sdstS 6.4 + small arrays ≈ 44.8 MB
  char* p = (char*)d_ws;
  unsigned short* hbf = (unsigned short*)p; p += (size_t)NNODES * NF * 2;
  unsigned short* agg = (unsigned short*)p; p += (size_t)NNODES * NF * 2;
  int2* sd8S  = (int2*)p;                   p += (size_t)NEDGES * 8;
  int*  sdstS = (int*)p;                    p += (size_t)NEDGES * 4;
  int*  gcnt  = (int*)p;                    p += 256 * 4;
  int*  boff  = (int*)p;                    p += 256 * 4;
  int*  bcur  = (int*)p;                    p += 256 * 4;

  // final sorted records live in d_out's dead space (overwritten by k_out at the end):
  // srec = {src, dist, dst, 0} int4, EPTOT*16B = 27.3 MB  (d_out is 51.2 MB)
  int4* srec = (int4*)d_out;

  hipMemsetAsync(gcnt, 0, 256 * sizeof(int), stream);
  hipMemsetAsync(agg, 0, sizeof(unsigned short) * (size_t)NNODES * NF, stream);

  k_lin1    <<<2048, 256, 0, stream>>>(x, l1w, hbf);
  k_bhist   <<<NCHK, 256, 0, stream>>>(ei, gcnt);
  k_bscan   <<<1, 256, 0, stream>>>(gcnt, boff, bcur);
  k_bscatter<<<NCHK, 256, 0, stream>>>(ei, ea, bcur, sd8S, sdstS);
  k_bsort   <<<NB, 256, 0, stream>>>(sd8S, sdstS, boff, srec);
  k_edge_mfma<<<NWAVES / 4, 256, 0, stream>>>(srec, hbf, e1w, e1b, e2w, e2b, agg);
  k_out     <<<2048, 256, 0, stream>>>(x, agg, l2w, l2b, out);
}

// Round 9
// 245.960 us; speedup vs baseline: 2.7071x; 1.3276x over previous
//
#include <hip/hip_runtime.h>
#include <hip/hip_bf16.h>

#define NNODES 100000
#define NEDGES 1600000
#define DIM    128
#define NF     64
#define NG     50
#define H1P    20        // h1buf row stride in shorts (0 conflicts measured r3-r8)
#define EPG    52        // edges per 16-lane group chunk (13 iters x 4)
#define EPW    208       // edges per wave (4 groups)
#define NWAVES 8192      // 2048 blocks x 4 waves
#define EPTOT  1703936   // NWAVES * EPW  (>= NEDGES, OOB slots masked)

#define BSH    9                         // bucket = dst >> 9 (512 nodes/bucket)
#define NB     ((NNODES + 511) >> 9)     // 196 buckets
#define CHK    8192                      // edges per block in bucket passes
#define NCHK   ((NEDGES + CHK - 1) / CHK)  // 196 blocks

constexpr float F_CUTOFF = 5.0f;
constexpr float F_DELTA  = F_CUTOFF / (NG - 1);
constexpr float F_COEFF  = -0.5f / (F_DELTA * F_DELTA);
constexpr float F_PI     = 3.14159265358979323846f;

typedef __attribute__((ext_vector_type(8))) short short8v;
typedef __attribute__((ext_vector_type(4))) float f32x4;
typedef __attribute__((ext_vector_type(2))) int int2v;

__device__ inline unsigned short f2bf(float x) {
  __hip_bfloat16 h = __float2bfloat16(x);
  return *reinterpret_cast<unsigned short*>(&h);
}
__device__ inline unsigned pkbf(float a, float b) {
  float2 f2; f2.x = a; f2.y = b;
  __hip_bfloat162 h2 = __float22bfloat162_rn(f2);
  return *reinterpret_cast<unsigned*>(&h2);
}
__device__ inline float bf2f(unsigned int lo16) {
  return __uint_as_float(lo16 << 16);
}

// ---------------- kernel 1 (MFMA): h[n][f] = sum_k x[n][k] * lin1_w[f][k]  (bf16 out) ----------------
// 16 nodes per wave-iteration. M=nodes(16), N=filters(64: 4 tiles), K=128 (4 steps of 32).
// Same verified fragment scheme as k_edge_mfma: k = s*32 + g*8 + i for both A and B;
// C/D: col = lane&15, row = (lane>>4)*4 + reg. B tiles filter-pair permuted
// (j = (t>>1)*32 + 2*lo + (t&1)) so the epilogue stores bf16 pairs as dwords.
__global__ __launch_bounds__(256, 2) void k_lin1_mfma(
    const float* __restrict__ x, const float* __restrict__ w1,
    unsigned short* __restrict__ h) {
  const int wave = threadIdx.x >> 6, lane = threadIdx.x & 63;
  const int lo = lane & 15, g = lane >> 4;

  // --- B fragments (one-time): B[k][j] = w1[j][k], j = (t>>1)*32 + 2*lo + (t&1)
  short8v B[4][4];
#pragma unroll
  for (int t = 0; t < 4; ++t) {
    const int j = (t >> 1) * 32 + 2 * lo + (t & 1);
#pragma unroll
    for (int s = 0; s < 4; ++s) {
      union { short8v v; unsigned u[4]; } bu;
      const float* wr = w1 + j * DIM + s * 32 + g * 8;
#pragma unroll
      for (int p = 0; p < 4; ++p)
        bu.u[p] = pkbf(wr[2 * p], wr[2 * p + 1]);
      B[t][s] = bu.v;
    }
  }

  const int nIter = NNODES / 16;   // 6250
  for (int it = blockIdx.x * 4 + wave; it < nIter; it += gridDim.x * 4) {
    const int n0 = it * 16;
    // --- A fragments: row = node n0+lo, k = s*32 + g*8 + i (f32 -> bf16 in-register)
    short8v A[4];
#pragma unroll
    for (int s = 0; s < 4; ++s) {
      const float4 va = *(const float4*)&x[(size_t)(n0 + lo) * DIM + s * 32 + g * 8];
      const float4 vb = *(const float4*)&x[(size_t)(n0 + lo) * DIM + s * 32 + g * 8 + 4];
      union { short8v v; unsigned u[4]; } au;
      au.u[0] = pkbf(va.x, va.y);
      au.u[1] = pkbf(va.z, va.w);
      au.u[2] = pkbf(vb.x, vb.y);
      au.u[3] = pkbf(vb.z, vb.w);
      A[s] = au.v;
    }
    // --- MFMA: acc[t][r] = h[node n0+g*4+r][filter j(t,lo)]
    f32x4 acc[4];
#pragma unroll
    for (int t = 0; t < 4; ++t) {
      f32x4 z = {0.f, 0.f, 0.f, 0.f};
      z = __builtin_amdgcn_mfma_f32_16x16x32_bf16(A[0], B[t][0], z, 0, 0, 0);
      z = __builtin_amdgcn_mfma_f32_16x16x32_bf16(A[1], B[t][1], z, 0, 0, 0);
      z = __builtin_amdgcn_mfma_f32_16x16x32_bf16(A[2], B[t][2], z, 0, 0, 0);
      z = __builtin_amdgcn_mfma_f32_16x16x32_bf16(A[3], B[t][3], z, 0, 0, 0);
      acc[t] = z;
    }
    // --- store: filters (2lo,2lo+1) and (32+2lo,33+2lo) as dwords
#pragma unroll
    for (int r = 0; r < 4; ++r) {
      unsigned short* hp = h + (size_t)(n0 + g * 4 + r) * NF + 2 * lo;
      *(unsigned*)(hp)      = pkbf(acc[0][r], acc[1][r]);
      *(unsigned*)(hp + 32) = pkbf(acc[2][r], acc[3][r]);
    }
  }
}

// ---------------- bucket histogram: per-block LDS counts, 196 global atomics/block ----------------
__global__ __launch_bounds__(256) void k_bhist(
    const int* __restrict__ ei, int* __restrict__ gcnt) {
  __shared__ int lcnt[NB];
  for (int i = threadIdx.x; i < NB; i += 256) lcnt[i] = 0;
  __syncthreads();
  const int base = blockIdx.x * CHK;
  for (int i = threadIdx.x; i < CHK; i += 256) {
    const int e = base + i;
    if (e < NEDGES) atomicAdd(&lcnt[ei[NEDGES + e] >> BSH], 1);
  }
  __syncthreads();
  for (int i = threadIdx.x; i < NB; i += 256)
    if (lcnt[i]) atomicAdd(&gcnt[i], lcnt[i]);
}

// ---------------- scan 196 bucket totals -> boff[0..NB] (exclusive) + cursor copy ----------------
__global__ __launch_bounds__(256) void k_bscan(
    const int* __restrict__ gcnt, int* __restrict__ boff, int* __restrict__ bcur) {
  __shared__ int sb[256];
  const int t = threadIdx.x;
  const int v = (t < NB) ? gcnt[t] : 0;
  sb[t] = v;
  __syncthreads();
  for (int off = 1; off < 256; off <<= 1) {
    const int xv = (t >= off) ? sb[t - off] : 0;
    __syncthreads();
    sb[t] += xv;
    __syncthreads();
  }
  if (t <= NB) {
    const int ex = sb[t] - v;
    boff[t] = ex;
    if (t < NB) bcur[t] = ex;
  }
}

// ---------------- pass 1: bucket-scatter with per-(block,bucket) contiguous chunks ----------------
__global__ __launch_bounds__(256) void k_bscatter(
    const int* __restrict__ ei, const float* __restrict__ ea,
    int* __restrict__ bcur, int2* __restrict__ sd8S, int* __restrict__ sdstS) {
  __shared__ int lcnt[NB];
  __shared__ int lcur[NB];
  for (int i = threadIdx.x; i < NB; i += 256) lcnt[i] = 0;
  __syncthreads();
  const int base = blockIdx.x * CHK;
  for (int i = threadIdx.x; i < CHK; i += 256) {
    const int e = base + i;
    if (e < NEDGES) atomicAdd(&lcnt[ei[NEDGES + e] >> BSH], 1);
  }
  __syncthreads();
  for (int i = threadIdx.x; i < NB; i += 256)
    lcur[i] = lcnt[i] ? atomicAdd(&bcur[i], lcnt[i]) : 0;
  __syncthreads();
  for (int i = threadIdx.x; i < CHK; i += 256) {
    const int e = base + i;
    if (e < NEDGES) {
      const int dst = ei[NEDGES + e];
      const int pos = atomicAdd(&lcur[dst >> BSH], 1);
      int2 r; r.x = ei[e]; r.y = __float_as_int(ea[e]);
      sd8S[pos]  = r;
      sdstS[pos] = dst;
    }
  }
}

// ---------------- pass 2: per-bucket LDS counting sort -> final dst-sorted records ----------------
__global__ __launch_bounds__(256) void k_bsort(
    const int2* __restrict__ sd8S, const int* __restrict__ sdstS,
    const int* __restrict__ boff, int4* __restrict__ srec) {
  __shared__ int cnt[512];
  __shared__ int red[256];
  const int b = blockIdx.x;
  const int t = threadIdx.x;
  const int s0 = boff[b], s1 = boff[b + 1];
  const int nodeBase = b << BSH;
  cnt[t] = 0; cnt[t + 256] = 0;
  __syncthreads();
  for (int i = s0 + t; i < s1; i += 256)
    atomicAdd(&cnt[sdstS[i] - nodeBase], 1);
  __syncthreads();
  const int v0 = cnt[2 * t], v1 = cnt[2 * t + 1];
  const int sum2 = v0 + v1;
  red[t] = sum2;
  __syncthreads();
  for (int off = 1; off < 256; off <<= 1) {
    const int xv = (t >= off) ? red[t - off] : 0;
    __syncthreads();
    red[t] += xv;
    __syncthreads();
  }
  const int ex = s0 + red[t] - sum2;
  cnt[2 * t]     = ex;
  cnt[2 * t + 1] = ex + v0;
  __syncthreads();
  for (int i = s0 + t; i < s1; i += 256) {
    const int2 r8 = sd8S[i];
    const int dst = sdstS[i];
    const int p = atomicAdd(&cnt[dst - nodeBase], 1);
    int4 r; r.x = r8.x; r.y = r8.y; r.z = dst; r.w = 0;
    srec[p] = r;
  }
}

// ---------------- kernel 2: MFMA edge MLP, group-contiguous sorted chunks, carry-run flush ----------------
__global__ __launch_bounds__(256, 2) void k_edge_mfma(
    const int4* __restrict__ srec, const unsigned short* __restrict__ hbf,
    const float* __restrict__ w1, const float* __restrict__ b1,
    const float* __restrict__ w2, const float* __restrict__ b2,
    unsigned short* __restrict__ agg) {
  __shared__ __align__(16) unsigned short h1buf[4][NF][H1P];

  const int wave = threadIdx.x >> 6, lane = threadIdx.x & 63;
  const int lo = lane & 15, g = lane >> 4;

  short8v B1[4][2];
#pragma unroll
  for (int t = 0; t < 4; ++t)
#pragma unroll
    for (int s = 0; s < 2; ++s) {
      short8v f8;
#pragma unroll
      for (int i = 0; i < 8; ++i) {
        const int gg = s * 32 + g * 8 + i;
        const int f  = t * 16 + lo;
        f8[i] = (gg < NG) ? (short)f2bf(w1[f * NG + gg]) : (short)0;
      }
      B1[t][s] = f8;
    }
  short8v B2[4][2];
#pragma unroll
  for (int t = 0; t < 4; ++t)
#pragma unroll
    for (int s = 0; s < 2; ++s) {
      short8v f8;
#pragma unroll
      for (int i = 0; i < 8; ++i) {
        const int f_in = s * 32 + g * 8 + i;
        const int j = (t >> 1) * 32 + 2 * lo + (t & 1);
        f8[i] = (short)f2bf(w2[j * NF + f_in]);
      }
      B2[t][s] = f8;
    }
  float b1v[4], b2v[4];
#pragma unroll
  for (int t = 0; t < 4; ++t) {
    b1v[t] = b1[t * 16 + lo];
    b2v[t] = b2[(t >> 1) * 32 + 2 * lo + (t & 1)];
  }

  const float l2e  = F_COEFF * 1.44269504088896341f;
  const float goff = (float)(g * 8) * F_DELTA;

  const int wid   = blockIdx.x * 4 + wave;
  const int gbase = wid * EPW + g * EPG;
  const int lbase = wid * EPW + (lo >> 2) * EPG + (lo & 3);

  int run_dst = -1;
  float c0 = 0.f, c1 = 0.f, c2 = 0.f, c3 = 0.f;

  int4 q0 = srec[gbase + 0];
  int4 q1 = srec[gbase + 1];
  int4 q2 = srec[gbase + 2];
  int4 q3 = srec[gbase + 3];
  float dnx = __int_as_float(srec[lbase].y);
  dnx = (lbase < NEDGES) ? dnx : 0.f;

#pragma unroll 1
  for (int it = 0; it < EPG / 4; ++it) {
    const int eg = gbase + it * 4;
    const int4 r0 = q0, r1 = q1, r2 = q2, r3 = q3;
    const float d = dnx;
    {
      const int itn = (it + 1 < EPG / 4) ? it + 1 : it;
      const int egn = gbase + itn * 4;
      q0 = srec[egn + 0]; q1 = srec[egn + 1];
      q2 = srec[egn + 2]; q3 = srec[egn + 3];
      const int lsn = lbase + itn * 4;
      float dn = __int_as_float(srec[lsn].y);
      dnx = (lsn < NEDGES) ? dn : 0.f;
    }

    int   sv[4] = {r0.x, r1.x, r2.x, r3.x};
    float dd[4] = {__int_as_float(r0.y), __int_as_float(r1.y),
                   __int_as_float(r2.y), __int_as_float(r3.y)};
    int   dv[4] = {r0.z, r1.z, r2.z, r3.z};
#pragma unroll
    for (int r = 0; r < 4; ++r) {
      const bool val = (eg + r) < NEDGES;
      sv[r] = val ? sv[r] : 0;
      dv[r] = val ? dv[r] : -1;
    }

    unsigned hp0[4], hp1[4];
#pragma unroll
    for (int r = 0; r < 4; ++r) {
      const unsigned short* hs = hbf + (size_t)sv[r] * NF + 2 * lo;
      hp0[r] = *(const unsigned*)(hs);
      hp1[r] = *(const unsigned*)(hs + 32);
    }

    short8v A1[2];
#pragma unroll
    for (int s = 0; s < 2; ++s) {
      union { short8v v; unsigned u[4]; } au;
#pragma unroll
      for (int p = 0; p < 4; ++p) {
        const float off0 = goff + (float)(s * 32 + 2 * p) * F_DELTA;
        const float t0 = d - off0;
        const float t1 = d - (off0 + F_DELTA);
        au.u[p] = pkbf(exp2f(l2e * t0 * t0), exp2f(l2e * t1 * t1));
      }
      A1[s] = au.v;
    }

    f32x4 acc1[4];
#pragma unroll
    for (int t = 0; t < 4; ++t) {
      f32x4 z = {0.f, 0.f, 0.f, 0.f};
      z = __builtin_amdgcn_mfma_f32_16x16x32_bf16(A1[0], B1[t][0], z, 0, 0, 0);
      z = __builtin_amdgcn_mfma_f32_16x16x32_bf16(A1[1], B1[t][1], z, 0, 0, 0);
      acc1[t] = z;
    }

#pragma unroll
    for (int t = 0; t < 4; ++t) {
      const float v0 = fmaxf(acc1[t][0] + b1v[t], 0.f);
      const float v1 = fmaxf(acc1[t][1] + b1v[t], 0.f);
      const float v2 = fmaxf(acc1[t][2] + b1v[t], 0.f);
      const float v3 = fmaxf(acc1[t][3] + b1v[t], 0.f);
      int2v pk;
      pk[0] = (int)pkbf(v0, v1);
      pk[1] = (int)pkbf(v2, v3);
      *(int2v*)&h1buf[wave][t * 16 + lo][g * 4] = pk;
    }

    short8v A2[2];
#pragma unroll
    for (int s = 0; s < 2; ++s) {
      short8v f8;
#pragma unroll
      for (int i = 0; i < 8; ++i)
        f8[i] = (short)h1buf[wave][s * 32 + g * 8 + i][lo];
      A2[s] = f8;
    }

    f32x4 acc2[4];
#pragma unroll
    for (int t = 0; t < 4; ++t) {
      f32x4 z = {0.f, 0.f, 0.f, 0.f};
      z = __builtin_amdgcn_mfma_f32_16x16x32_bf16(A2[0], B2[t][0], z, 0, 0, 0);
      z = __builtin_amdgcn_mfma_f32_16x16x32_bf16(A2[1], B2[t][1], z, 0, 0, 0);
      acc2[t] = z;
    }

#pragma unroll
    for (int r = 0; r < 4; ++r) {
      const float C  = 0.5f * (__cosf(dd[r] * (F_PI / F_CUTOFF)) + 1.0f);
      const float m0 = bf2f(hp0[r] & 0xffffu) * ((acc2[0][r] + b2v[0]) * C);
      const float m1 = bf2f(hp0[r] >> 16)     * ((acc2[1][r] + b2v[1]) * C);
      const float m2 = bf2f(hp1[r] & 0xffffu) * ((acc2[2][r] + b2v[2]) * C);
      const float m3 = bf2f(hp1[r] >> 16)     * ((acc2[3][r] + b2v[3]) * C);
      if (dv[r] != run_dst) {
        if (run_dst >= 0) {
          unsigned short* ap = agg + (size_t)run_dst * NF + 2 * lo;
          const unsigned k0 = pkbf(c0, c1), k1 = pkbf(c2, c3);
          asm volatile("global_atomic_pk_add_bf16 %0, %1, off" :: "v"(ap), "v"(k0));
          asm volatile("global_atomic_pk_add_bf16 %0, %1, off" :: "v"(ap + 32), "v"(k1));
        }
        c0 = 0.f; c1 = 0.f; c2 = 0.f; c3 = 0.f;
        run_dst = dv[r];
      }
      c0 += m0; c1 += m1; c2 += m2; c3 += m3;
    }
  }
  if (run_dst >= 0) {
    unsigned short* ap = agg + (size_t)run_dst * NF + 2 * lo;
    const unsigned k0 = pkbf(c0, c1), k1 = pkbf(c2, c3);
    asm volatile("global_atomic_pk_add_bf16 %0, %1, off" :: "v"(ap), "v"(k0));
    asm volatile("global_atomic_pk_add_bf16 %0, %1, off" :: "v"(ap + 32), "v"(k1));
  }
}

// ---------------- kernel 3: out[n][d] = x[n][d] + relu(b[d] + agg[n,:] . lin2_w[d,:]) ----------------
__global__ __launch_bounds__(256) void k_out(
    const float* __restrict__ x, const unsigned short* __restrict__ agg,
    const float* __restrict__ w2, const float* __restrict__ b,
    float* __restrict__ out) {
  __shared__ __align__(16) float sw[DIM][NF + 4];
  __shared__ __align__(16) float sa[4][4][NF];
  for (int i = threadIdx.x; i < DIM * NF; i += 256)
    sw[i >> 6][i & 63] = w2[i];
  __syncthreads();
  const int wave = threadIdx.x >> 6, lane = threadIdx.x & 63;
  const float bias0 = b[lane], bias1 = b[lane + 64];
  const int nIter = NNODES / 4;
  for (int it = blockIdx.x * 4 + wave; it < nIter; it += gridDim.x * 4) {
    const int n0 = it * 4;
#pragma unroll
    for (int i = 0; i < 4; ++i)
      sa[wave][i][lane] = bf2f((unsigned)agg[(size_t)(n0 + i) * NF + lane]);
    float acc[8];
#pragma unroll
    for (int i = 0; i < 4; ++i) { acc[2 * i] = bias0; acc[2 * i + 1] = bias1; }
#pragma unroll
    for (int j4 = 0; j4 < NF / 4; ++j4) {
      const float4 wv0 = *(const float4*)&sw[lane][j4 * 4];
      const float4 wv1 = *(const float4*)&sw[lane + 64][j4 * 4];
#pragma unroll
      for (int i = 0; i < 4; ++i) {
        const float4 av = *(const float4*)&sa[wave][i][j4 * 4];
        acc[2 * i]     = fmaf(wv0.x, av.x, acc[2 * i]);
        acc[2 * i]     = fmaf(wv0.y, av.y, acc[2 * i]);
        acc[2 * i]     = fmaf(wv0.z, av.z, acc[2 * i]);
        acc[2 * i]     = fmaf(wv0.w, av.w, acc[2 * i]);
        acc[2 * i + 1] = fmaf(wv1.x, av.x, acc[2 * i + 1]);
        acc[2 * i + 1] = fmaf(wv1.y, av.y, acc[2 * i + 1]);
        acc[2 * i + 1] = fmaf(wv1.z, av.z, acc[2 * i + 1]);
        acc[2 * i + 1] = fmaf(wv1.w, av.w, acc[2 * i + 1]);
      }
    }
#pragma unroll
    for (int i = 0; i < 4; ++i) {
      const size_t base = (size_t)(n0 + i) * DIM;
      out[base + lane]      = x[base + lane]      + fmaxf(acc[2 * i],     0.f);
      out[base + 64 + lane] = x[base + 64 + lane] + fmaxf(acc[2 * i + 1], 0.f);
    }
  }
}

extern "C" void kernel_launch(void* const* d_in, const int* in_sizes, int n_in,
                              void* d_out, int out_size, void* d_ws, size_t ws_size,
                              hipStream_t stream) {
  const float* x   = (const float*)d_in[0];
  const int*   ei  = (const int*)  d_in[1];
  const float* ea  = (const float*)d_in[3];   // edge_attr == edge_weight (same dist)
  const float* l1w = (const float*)d_in[4];
  const float* l2w = (const float*)d_in[5];
  const float* l2b = (const float*)d_in[6];
  const float* e1w = (const float*)d_in[7];
  const float* e1b = (const float*)d_in[8];
  const float* e2w = (const float*)d_in[9];
  const float* e2b = (const float*)d_in[10];
  float* out = (float*)d_out;

  // ws carve: hbf 12.8 + agg 12.8 + staging sd8S 12.8 + sdstS 6.4 + small arrays
  char* p = (char*)d_ws;
  unsigned short* hbf = (unsigned short*)p; p += (size_t)NNODES * NF * 2;
  unsigned short* agg = (unsigned short*)p; p += (size_t)NNODES * NF * 2;
  int2* sd8S  = (int2*)p;                   p += (size_t)NEDGES * 8;
  int*  sdstS = (int*)p;                    p += (size_t)NEDGES * 4;
  int*  gcnt  = (int*)p;                    p += 256 * 4;
  int*  boff  = (int*)p;                    p += 256 * 4;
  int*  bcur  = (int*)p;                    p += 256 * 4;

  // final sorted records live in d_out's dead space (overwritten by k_out at the end)
  int4* srec = (int4*)d_out;

  hipMemsetAsync(gcnt, 0, 256 * sizeof(int), stream);
  hipMemsetAsync(agg, 0, sizeof(unsigned short) * (size_t)NNODES * NF, stream);

  k_lin1_mfma<<<512, 256, 0, stream>>>(x, l1w, hbf);
  k_bhist   <<<NCHK, 256, 0, stream>>>(ei, gcnt);
  k_bscan   <<<1, 256, 0, stream>>>(gcnt, boff, bcur);
  k_bscatter<<<NCHK, 256, 0, stream>>>(ei, ea, bcur, sd8S, sdstS);
  k_bsort   <<<NB, 256, 0, stream>>>(sd8S, sdstS, boff, srec);
  k_edge_mfma<<<NWAVES / 4, 256, 0, stream>>>(srec, hbf, e1w, e1b, e2w, e2b, agg);
  k_out     <<<2048, 256, 0, stream>>>(x, agg, l2w, l2b, out);
}

// Round 10
// 202.136 us; speedup vs baseline: 3.2940x; 1.2168x over previous
//
#include <hip/hip_runtime.h>
#include <hip/hip_bf16.h>

#define NNODES 100000
#define NEDGES 1600000
#define DIM    128
#define NF     64
#define NG     50
#define EPG    52        // edges per 16-lane group chunk (13 iters x 4)
#define EPW    208       // edges per wave (4 groups)
#define NWAVES 8192      // 2048 blocks x 4 waves
#define EPTOT  1703936   // NWAVES * EPW  (>= NEDGES, OOB slots masked)

#define BSH    9                         // bucket = dst >> 9 (512 nodes/bucket)
#define NB     ((NNODES + 511) >> 9)     // 196 buckets
#define CHK    8192                      // edges per block in bucket passes
#define NCHK   ((NEDGES + CHK - 1) / CHK)  // 196 blocks

#define NBIN   16385                     // table rows: bin = round(d * 16384/5), d in [0,5]

constexpr float F_CUTOFF = 5.0f;
constexpr float F_DELTA  = F_CUTOFF / (NG - 1);
constexpr float F_COEFF  = -0.5f / (F_DELTA * F_DELTA);
constexpr float F_PI     = 3.14159265358979323846f;
constexpr float TSCALE   = 16384.0f / F_CUTOFF;

typedef __attribute__((ext_vector_type(8))) short short8v;
typedef __attribute__((ext_vector_type(4))) float f32x4;

__device__ inline unsigned short f2bf(float x) {
  __hip_bfloat16 h = __float2bfloat16(x);
  return *reinterpret_cast<unsigned short*>(&h);
}
__device__ inline unsigned pkbf(float a, float b) {
  float2 f2; f2.x = a; f2.y = b;
  __hip_bfloat162 h2 = __float22bfloat162_rn(f2);
  return *reinterpret_cast<unsigned*>(&h2);
}
__device__ inline float bf2f(unsigned int lo16) {
  return __uint_as_float(lo16 << 16);
}

// ---------------- kernel 1 (MFMA): h[n][f] = sum_k x[n][k] * lin1_w[f][k]  (bf16 out) ----------------
// Verified fragment scheme: k = s*32 + g*8 + i for A and B; C/D: col = lane&15,
// row = (lane>>4)*4 + reg. B tiles filter-pair permuted (j = (t>>1)*32 + 2*lo + (t&1)).
__global__ __launch_bounds__(256, 2) void k_lin1_mfma(
    const float* __restrict__ x, const float* __restrict__ w1,
    unsigned short* __restrict__ h) {
  const int wave = threadIdx.x >> 6, lane = threadIdx.x & 63;
  const int lo = lane & 15, g = lane >> 4;

  short8v B[4][4];
#pragma unroll
  for (int t = 0; t < 4; ++t) {
    const int j = (t >> 1) * 32 + 2 * lo + (t & 1);
#pragma unroll
    for (int s = 0; s < 4; ++s) {
      union { short8v v; unsigned u[4]; } bu;
      const float* wr = w1 + j * DIM + s * 32 + g * 8;
#pragma unroll
      for (int p = 0; p < 4; ++p)
        bu.u[p] = pkbf(wr[2 * p], wr[2 * p + 1]);
      B[t][s] = bu.v;
    }
  }

  const int nIter = NNODES / 16;   // 6250
  for (int it = blockIdx.x * 4 + wave; it < nIter; it += gridDim.x * 4) {
    const int n0 = it * 16;
    short8v A[4];
#pragma unroll
    for (int s = 0; s < 4; ++s) {
      const float4 va = *(const float4*)&x[(size_t)(n0 + lo) * DIM + s * 32 + g * 8];
      const float4 vb = *(const float4*)&x[(size_t)(n0 + lo) * DIM + s * 32 + g * 8 + 4];
      union { short8v v; unsigned u[4]; } au;
      au.u[0] = pkbf(va.x, va.y);
      au.u[1] = pkbf(va.z, va.w);
      au.u[2] = pkbf(vb.x, vb.y);
      au.u[3] = pkbf(vb.z, vb.w);
      A[s] = au.v;
    }
    f32x4 acc[4];
#pragma unroll
    for (int t = 0; t < 4; ++t) {
      f32x4 z = {0.f, 0.f, 0.f, 0.f};
      z = __builtin_amdgcn_mfma_f32_16x16x32_bf16(A[0], B[t][0], z, 0, 0, 0);
      z = __builtin_amdgcn_mfma_f32_16x16x32_bf16(A[1], B[t][1], z, 0, 0, 0);
      z = __builtin_amdgcn_mfma_f32_16x16x32_bf16(A[2], B[t][2], z, 0, 0, 0);
      z = __builtin_amdgcn_mfma_f32_16x16x32_bf16(A[3], B[t][3], z, 0, 0, 0);
      acc[t] = z;
    }
#pragma unroll
    for (int r = 0; r < 4; ++r) {
      unsigned short* hp = h + (size_t)(n0 + g * 4 + r) * NF + 2 * lo;
      *(unsigned*)(hp)      = pkbf(acc[0][r], acc[1][r]);
      *(unsigned*)(hp + 32) = pkbf(acc[2][r], acc[3][r]);
    }
  }
}

// ---------------- edge-filter table: T[bin][j] = C(d)*(enn2(relu(enn1(smear(d)))) + b2), d = bin*5/16384 ----------------
__global__ __launch_bounds__(256) void k_table(
    const float* __restrict__ w1, const float* __restrict__ b1,
    const float* __restrict__ w2, const float* __restrict__ b2,
    unsigned short* __restrict__ tab) {
  __shared__ float ssm[4][56];   // per-wave smear values
  __shared__ float sh1[4][64];   // per-wave relu(h1)
  const int wave = threadIdx.x >> 6, lane = threadIdx.x & 63;
  const int wid = blockIdx.x * 4 + wave;
  const float b1v = b1[lane], b2v = b2[lane];
  for (int bin = wid; bin < NBIN; bin += 1024) {
    const float d = (float)bin * (F_CUTOFF / 16384.0f);
    if (lane < NG) {
      const float t0 = d - (float)lane * F_DELTA;
      ssm[wave][lane] = __expf(F_COEFF * t0 * t0);
    }
    float h1 = b1v;                 // compiler-inserted lgkmcnt orders the same-array LDS dep
#pragma unroll
    for (int gg = 0; gg < NG; ++gg)
      h1 = fmaf(ssm[wave][gg], w1[lane * NG + gg], h1);
    sh1[wave][lane] = fmaxf(h1, 0.f);
    float wv = b2v;
#pragma unroll
    for (int f = 0; f < NF; ++f)
      wv = fmaf(sh1[wave][f], w2[lane * NF + f], wv);
    const float C = 0.5f * (__cosf(d * (F_PI / F_CUTOFF)) + 1.0f);
    tab[(size_t)bin * NF + lane] = f2bf(wv * C);
  }
}

// ---------------- bucket histogram ----------------
__global__ __launch_bounds__(256) void k_bhist(
    const int* __restrict__ ei, int* __restrict__ gcnt) {
  __shared__ int lcnt[NB];
  for (int i = threadIdx.x; i < NB; i += 256) lcnt[i] = 0;
  __syncthreads();
  const int base = blockIdx.x * CHK;
  for (int i = threadIdx.x; i < CHK; i += 256) {
    const int e = base + i;
    if (e < NEDGES) atomicAdd(&lcnt[ei[NEDGES + e] >> BSH], 1);
  }
  __syncthreads();
  for (int i = threadIdx.x; i < NB; i += 256)
    if (lcnt[i]) atomicAdd(&gcnt[i], lcnt[i]);
}

// ---------------- scan bucket totals -> boff (exclusive) + cursor copy ----------------
__global__ __launch_bounds__(256) void k_bscan(
    const int* __restrict__ gcnt, int* __restrict__ boff, int* __restrict__ bcur) {
  __shared__ int sb[256];
  const int t = threadIdx.x;
  const int v = (t < NB) ? gcnt[t] : 0;
  sb[t] = v;
  __syncthreads();
  for (int off = 1; off < 256; off <<= 1) {
    const int xv = (t >= off) ? sb[t - off] : 0;
    __syncthreads();
    sb[t] += xv;
    __syncthreads();
  }
  if (t <= NB) {
    const int ex = sb[t] - v;
    boff[t] = ex;
    if (t < NB) bcur[t] = ex;
  }
}

// ---------------- pass 1: bucket-scatter with per-(block,bucket) contiguous chunks ----------------
__global__ __launch_bounds__(256) void k_bscatter(
    const int* __restrict__ ei, const float* __restrict__ ea,
    int* __restrict__ bcur, int2* __restrict__ sd8S, int* __restrict__ sdstS) {
  __shared__ int lcnt[NB];
  __shared__ int lcur[NB];
  for (int i = threadIdx.x; i < NB; i += 256) lcnt[i] = 0;
  __syncthreads();
  const int base = blockIdx.x * CHK;
  for (int i = threadIdx.x; i < CHK; i += 256) {
    const int e = base + i;
    if (e < NEDGES) atomicAdd(&lcnt[ei[NEDGES + e] >> BSH], 1);
  }
  __syncthreads();
  for (int i = threadIdx.x; i < NB; i += 256)
    lcur[i] = lcnt[i] ? atomicAdd(&bcur[i], lcnt[i]) : 0;
  __syncthreads();
  for (int i = threadIdx.x; i < CHK; i += 256) {
    const int e = base + i;
    if (e < NEDGES) {
      const int dst = ei[NEDGES + e];
      const int pos = atomicAdd(&lcur[dst >> BSH], 1);
      int2 r; r.x = ei[e]; r.y = __float_as_int(ea[e]);
      sd8S[pos]  = r;
      sdstS[pos] = dst;
    }
  }
}

// ---------------- pass 2: per-bucket LDS counting sort -> final dst-sorted records ----------------
__global__ __launch_bounds__(256) void k_bsort(
    const int2* __restrict__ sd8S, const int* __restrict__ sdstS,
    const int* __restrict__ boff, int4* __restrict__ srec) {
  __shared__ int cnt[512];
  __shared__ int red[256];
  const int b = blockIdx.x;
  const int t = threadIdx.x;
  const int s0 = boff[b], s1 = boff[b + 1];
  const int nodeBase = b << BSH;
  cnt[t] = 0; cnt[t + 256] = 0;
  __syncthreads();
  for (int i = s0 + t; i < s1; i += 256)
    atomicAdd(&cnt[sdstS[i] - nodeBase], 1);
  __syncthreads();
  const int v0 = cnt[2 * t], v1 = cnt[2 * t + 1];
  const int sum2 = v0 + v1;
  red[t] = sum2;
  __syncthreads();
  for (int off = 1; off < 256; off <<= 1) {
    const int xv = (t >= off) ? red[t - off] : 0;
    __syncthreads();
    red[t] += xv;
    __syncthreads();
  }
  const int ex = s0 + red[t] - sum2;
  cnt[2 * t]     = ex;
  cnt[2 * t + 1] = ex + v0;
  __syncthreads();
  for (int i = s0 + t; i < s1; i += 256) {
    const int2 r8 = sd8S[i];
    const int dst = sdstS[i];
    const int p = atomicAdd(&cnt[dst - nodeBase], 1);
    int4 r; r.x = r8.x; r.y = r8.y; r.z = dst; r.w = 0;
    srec[p] = r;
  }
}

// ---------------- kernel 2: table-lookup edge messages + carry-run flush ----------------
// Each 16-lane group owns EPG=52 consecutive sorted edges (4/iter). Per edge:
// bin(d) -> 2 coalesced table dwords/lane (group-uniform row), 2 gather dwords from
// h[src], 4 multiplies; run sums carried across iters, flushed with 2 pk-bf16 atomics
// per dst change. Lane lo covers filters (2lo,2lo+1) and (32+2lo,33+2lo).
__global__ __launch_bounds__(256) void k_edge_tab(
    const int4* __restrict__ srec, const unsigned short* __restrict__ hbf,
    const unsigned* __restrict__ tab, unsigned short* __restrict__ agg) {
  const int wave = threadIdx.x >> 6, lane = threadIdx.x & 63;
  const int lo = lane & 15, g = lane >> 4;

  const int wid   = blockIdx.x * 4 + wave;
  const int gbase = wid * EPW + g * EPG;

  int run_dst = -1;
  float c0 = 0.f, c1 = 0.f, c2 = 0.f, c3 = 0.f;

  int4 q0 = srec[gbase + 0];
  int4 q1 = srec[gbase + 1];
  int4 q2 = srec[gbase + 2];
  int4 q3 = srec[gbase + 3];

#pragma unroll 1
  for (int it = 0; it < EPG / 4; ++it) {
    const int eg = gbase + it * 4;
    const int4 r0 = q0, r1 = q1, r2 = q2, r3 = q3;
    {
      const int itn = (it + 1 < EPG / 4) ? it + 1 : it;
      const int egn = gbase + itn * 4;
      q0 = srec[egn + 0]; q1 = srec[egn + 1];
      q2 = srec[egn + 2]; q3 = srec[egn + 3];
    }

    int   sv[4] = {r0.x, r1.x, r2.x, r3.x};
    float dd[4] = {__int_as_float(r0.y), __int_as_float(r1.y),
                   __int_as_float(r2.y), __int_as_float(r3.y)};
    int   dv[4] = {r0.z, r1.z, r2.z, r3.z};
#pragma unroll
    for (int r = 0; r < 4; ++r) {
      const bool val = (eg + r) < NEDGES;
      sv[r] = val ? sv[r] : 0;     // clamp gather address into hbf
      dv[r] = val ? dv[r] : -1;    // sentinel: never flushed
    }

    // ---- gathers (issued early; consumed in the message loop)
    unsigned hp0[4], hp1[4];
#pragma unroll
    for (int r = 0; r < 4; ++r) {
      const unsigned short* hs = hbf + (size_t)sv[r] * NF + 2 * lo;
      hp0[r] = *(const unsigned*)(hs);
      hp1[r] = *(const unsigned*)(hs + 32);
    }

    // ---- table rows (bin group-uniform -> 64B coalesced per load)
    unsigned tw0[4], tw1[4];
#pragma unroll
    for (int r = 0; r < 4; ++r) {
      const float dcl = fminf(fmaxf(dd[r], 0.f), F_CUTOFF);
      int bn = (int)(dcl * TSCALE + 0.5f);
      bn = (bn > 16384) ? 16384 : bn;
      const unsigned* trow = tab + (size_t)bn * (NF / 2);
      tw0[r] = trow[lo];
      tw1[r] = trow[16 + lo];
    }

    // ---- messages + run-carry; flush only on dst change (group-uniform branch)
#pragma unroll
    for (int r = 0; r < 4; ++r) {
      const float m0 = bf2f(hp0[r] & 0xffffu) * bf2f(tw0[r] & 0xffffu);
      const float m1 = bf2f(hp0[r] >> 16)     * bf2f(tw0[r] >> 16);
      const float m2 = bf2f(hp1[r] & 0xffffu) * bf2f(tw1[r] & 0xffffu);
      const float m3 = bf2f(hp1[r] >> 16)     * bf2f(tw1[r] >> 16);
      if (dv[r] != run_dst) {
        if (run_dst >= 0) {
          unsigned short* ap = agg + (size_t)run_dst * NF + 2 * lo;
          const unsigned k0 = pkbf(c0, c1), k1 = pkbf(c2, c3);
          asm volatile("global_atomic_pk_add_bf16 %0, %1, off" :: "v"(ap), "v"(k0));
          asm volatile("global_atomic_pk_add_bf16 %0, %1, off" :: "v"(ap + 32), "v"(k1));
        }
        c0 = 0.f; c1 = 0.f; c2 = 0.f; c3 = 0.f;
        run_dst = dv[r];
      }
      c0 += m0; c1 += m1; c2 += m2; c3 += m3;
    }
  }
  if (run_dst >= 0) {
    unsigned short* ap = agg + (size_t)run_dst * NF + 2 * lo;
    const unsigned k0 = pkbf(c0, c1), k1 = pkbf(c2, c3);
    asm volatile("global_atomic_pk_add_bf16 %0, %1, off" :: "v"(ap), "v"(k0));
    asm volatile("global_atomic_pk_add_bf16 %0, %1, off" :: "v"(ap + 32), "v"(k1));
  }
}

// ---------------- kernel 3: out[n][d] = x[n][d] + relu(b[d] + agg[n,:] . lin2_w[d,:]) ----------------
__global__ __launch_bounds__(256) void k_out(
    const float* __restrict__ x, const unsigned short* __restrict__ agg,
    const float* __restrict__ w2, const float* __restrict__ b,
    float* __restrict__ out) {
  __shared__ __align__(16) float sw[DIM][NF + 4];
  __shared__ __align__(16) float sa[4][4][NF];
  for (int i = threadIdx.x; i < DIM * NF; i += 256)
    sw[i >> 6][i & 63] = w2[i];
  __syncthreads();
  const int wave = threadIdx.x >> 6, lane = threadIdx.x & 63;
  const float bias0 = b[lane], bias1 = b[lane + 64];
  const int nIter = NNODES / 4;
  for (int it = blockIdx.x * 4 + wave; it < nIter; it += gridDim.x * 4) {
    const int n0 = it * 4;
#pragma unroll
    for (int i = 0; i < 4; ++i)
      sa[wave][i][lane] = bf2f((unsigned)agg[(size_t)(n0 + i) * NF + lane]);
    float acc[8];
#pragma unroll
    for (int i = 0; i < 4; ++i) { acc[2 * i] = bias0; acc[2 * i + 1] = bias1; }
#pragma unroll
    for (int j4 = 0; j4 < NF / 4; ++j4) {
      const float4 wv0 = *(const float4*)&sw[lane][j4 * 4];
      const float4 wv1 = *(const float4*)&sw[lane + 64][j4 * 4];
#pragma unroll
      for (int i = 0; i < 4; ++i) {
        const float4 av = *(const float4*)&sa[wave][i][j4 * 4];
        acc[2 * i]     = fmaf(wv0.x, av.x, acc[2 * i]);
        acc[2 * i]     = fmaf(wv0.y, av.y, acc[2 * i]);
        acc[2 * i]     = fmaf(wv0.z, av.z, acc[2 * i]);
        acc[2 * i]     = fmaf(wv0.w, av.w, acc[2 * i]);
        acc[2 * i + 1] = fmaf(wv1.x, av.x, acc[2 * i + 1]);
        acc[2 * i + 1] = fmaf(wv1.y, av.y, acc[2 * i + 1]);
        acc[2 * i + 1] = fmaf(wv1.z, av.z, acc[2 * i + 1]);
        acc[2 * i + 1] = fmaf(wv1.w, av.w, acc[2 * i + 1]);
      }
    }
#pragma unroll
    for (int i = 0; i < 4; ++i) {
      const size_t base = (size_t)(n0 + i) * DIM;
      out[base + lane]      = x[base + lane]      + fmaxf(acc[2 * i],     0.f);
      out[base + 64 + lane] = x[base + 64 + lane] + fmaxf(acc[2 * i + 1], 0.f);
    }
  }
}

extern "C" void kernel_launch(void* const* d_in, const int* in_sizes, int n_in,
                              void* d_out, int out_size, void* d_ws, size_t ws_size,
                              hipStream_t stream) {
  const float* x   = (const float*)d_in[0];
  const int*   ei  = (const int*)  d_in[1];
  const float* ea  = (const float*)d_in[3];   // edge_attr == edge_weight (same dist)
  const float* l1w = (const float*)d_in[4];
  const float* l2w = (const float*)d_in[5];
  const float* l2b = (const float*)d_in[6];
  const float* e1w = (const float*)d_in[7];
  const float* e1b = (const float*)d_in[8];
  const float* e2w = (const float*)d_in[9];
  const float* e2b = (const float*)d_in[10];
  float* out = (float*)d_out;

  // ws carve: hbf 12.8 + agg 12.8 + sd8S 12.8 + sdstS 6.4 + table 2.1 + small ≈ 47 MB
  char* p = (char*)d_ws;
  unsigned short* hbf = (unsigned short*)p; p += (size_t)NNODES * NF * 2;
  unsigned short* agg = (unsigned short*)p; p += (size_t)NNODES * NF * 2;
  int2* sd8S  = (int2*)p;                   p += (size_t)NEDGES * 8;
  int*  sdstS = (int*)p;                    p += (size_t)NEDGES * 4;
  unsigned short* tab = (unsigned short*)p; p += (size_t)16512 * NF * 2;
  int*  gcnt  = (int*)p;                    p += 256 * 4;
  int*  boff  = (int*)p;                    p += 256 * 4;
  int*  bcur  = (int*)p;                    p += 256 * 4;

  // final sorted records live in d_out's dead space (overwritten by k_out at the end)
  int4* srec = (int4*)d_out;

  hipMemsetAsync(gcnt, 0, 256 * sizeof(int), stream);
  hipMemsetAsync(agg, 0, sizeof(unsigned short) * (size_t)NNODES * NF, stream);

  k_table   <<<256, 256, 0, stream>>>(e1w, e1b, e2w, e2b, tab);
  k_lin1_mfma<<<512, 256, 0, stream>>>(x, l1w, hbf);
  k_bhist   <<<NCHK, 256, 0, stream>>>(ei, gcnt);
  k_bscan   <<<1, 256, 0, stream>>>(gcnt, boff, bcur);
  k_bscatter<<<NCHK, 256, 0, stream>>>(ei, ea, bcur, sd8S, sdstS);
  k_bsort   <<<NB, 256, 0, stream>>>(sd8S, sdstS, boff, srec);
  k_edge_tab<<<NWAVES / 4, 256, 0, stream>>>((const int4*)srec, hbf, (const unsigned*)tab, agg);
  k_out     <<<2048, 256, 0, stream>>>(x, agg, l2w, l2b, out);
}